// Round 1
// baseline (1502.128 us; speedup 1.0000x reference)
//
#include <hip/hip_runtime.h>

// R1: full correct pipeline. fp16 MFMA for all GEMM-shaped work (fp32 accum),
// exact fp32 sequential GRU (the expected bottleneck, ~480us: 4 chains, 1 wave
// each, readlane-broadcast matvec). Next rounds: packed-f16 GRU, GEMM pipeline.

namespace {

constexpr int B_ = 2, T_ = 2048, E_ = 1024, H_ = 16, HD_ = 64, G3_ = 192, M_ = B_ * T_;

typedef _Float16 f16;
typedef _Float16 f16x8 __attribute__((ext_vector_type(8)));
typedef _Float16 f16x4 __attribute__((ext_vector_type(4)));
typedef float f32x4 __attribute__((ext_vector_type(4)));

__device__ __forceinline__ f32x4 mfma16(f16x8 a, f16x8 b, f32x4 c) {
  return __builtin_amdgcn_mfma_f32_16x16x32_f16(a, b, c, 0, 0, 0);
}

// ---------------- fp32 -> fp16 convert ----------------
__global__ __launch_bounds__(256) void k_cvt(const float* __restrict__ s,
                                             f16* __restrict__ d, int n) {
  int i = (blockIdx.x * 256 + threadIdx.x) * 4;
  if (i < n) {
    float4 v = *(const float4*)(s + i);
    f16x4 o = {(f16)v.x, (f16)v.y, (f16)v.z, (f16)v.w};
    *(f16x4*)(d + i) = o;
  }
}

// ---------------- prep: v = silu(x)*emb, x_proj pooling, xw = pool16(x)@wih^T
__global__ __launch_bounds__(256) void k_prep(
    const float* __restrict__ x, const int* __restrict__ tok,
    const f16* __restrict__ wihq, const f16* __restrict__ wihk,
    const float* __restrict__ v_emb,
    f16* __restrict__ vh, f16* __restrict__ aq, f16* __restrict__ ak,
    float* __restrict__ xwq, float* __restrict__ xwk) {
  __shared__ float xs[E_];
  __shared__ float xp[64];
  const int row = blockIdx.x;
  const int b = row >> 11, t = row & (T_ - 1);
  const int tid = threadIdx.x;
  const float* xrow = x + (size_t)row * E_;
  {
    const int tk = tok[row];
    float4 xv = ((const float4*)xrow)[tid];
    ((float4*)xs)[tid] = xv;
    float4 ev = ((const float4*)(v_emb + (size_t)tk * E_))[tid];
    f16x4 o;
    o[0] = (f16)(xv.x / (1.f + __expf(-xv.x)) * ev.x);
    o[1] = (f16)(xv.y / (1.f + __expf(-xv.y)) * ev.y);
    o[2] = (f16)(xv.z / (1.f + __expf(-xv.z)) * ev.z);
    o[3] = (f16)(xv.w / (1.f + __expf(-xv.w)) * ev.w);
    const int e0 = tid * 4;
    const size_t voff = ((size_t)(b * H_ + (e0 >> 6)) * T_ + t) * HD_ + (e0 & 63);
    *(f16x4*)(vh + voff) = o;
  }
  __syncthreads();
  if (tid < 64) {
    float s = 0.f;
#pragma unroll
    for (int j = 0; j < 16; ++j) s += xs[tid * 16 + j];
    xp[tid] = s * (1.f / 16.f);
  }
  // adaptive pool 1024 -> 960 on feature dim (window 1 or 2)
  for (int i = tid; i < 960; i += 256) {
    int s0 = (i * 1024) / 960;
    int e0 = ((i + 1) * 1024 + 959) / 960;
    float m = xs[s0];
    if (e0 - s0 == 2) m = (m + xs[s0 + 1]) * 0.5f;
    f16 hv = (f16)m;
    aq[(size_t)row * E_ + 64 + i] = hv;
    ak[(size_t)row * E_ + 64 + i] = hv;
  }
  __syncthreads();
  // xw[g] = sum_d xp[d] * wih[g][d], for both chains
  for (int o = tid; o < 2 * G3_; o += 256) {
    const int chain = o / G3_, g = o % G3_;
    const f16* wrow = (chain ? wihk : wihq) + g * 64;
    float acc = 0.f;
#pragma unroll
    for (int c = 0; c < 8; ++c) {
      f16x8 wv = *(const f16x8*)(wrow + c * 8);
#pragma unroll
      for (int u = 0; u < 8; ++u) acc += xp[c * 8 + u] * (float)wv[u];
    }
    (chain ? xwk : xwq)[(size_t)row * G3_ + g] = acc;
  }
}

// ---------------- GRU: 4 independent chains (q/k x b0/b1), 1 wave each ------
// lane j holds h[j]; per step: readlane-broadcast h, 192 FMA; exact fp32.
__global__ __launch_bounds__(64, 1) void k_gru(
    const float* __restrict__ xwq, const float* __restrict__ xwk,
    const float* __restrict__ whhq, const float* __restrict__ whhk,
    f16* __restrict__ aq, f16* __restrict__ ak) {
  const int blk = blockIdx.x;
  const int chain = blk >> 1, b = blk & 1;
  const float* xw = (chain ? xwk : xwq) + (size_t)b * T_ * G3_;
  const float* whh = chain ? whhk : whhq;
  f16* a = (chain ? ak : aq) + (size_t)b * T_ * E_;
  const int j = threadIdx.x;
  float wr[64], wz[64], wn[64];
#pragma unroll
  for (int d4 = 0; d4 < 16; ++d4) {
    float4 r4 = *(const float4*)(whh + (size_t)j * 64 + d4 * 4);
    float4 z4 = *(const float4*)(whh + (size_t)(64 + j) * 64 + d4 * 4);
    float4 n4 = *(const float4*)(whh + (size_t)(128 + j) * 64 + d4 * 4);
    wr[d4 * 4 + 0] = r4.x; wr[d4 * 4 + 1] = r4.y; wr[d4 * 4 + 2] = r4.z; wr[d4 * 4 + 3] = r4.w;
    wz[d4 * 4 + 0] = z4.x; wz[d4 * 4 + 1] = z4.y; wz[d4 * 4 + 2] = z4.z; wz[d4 * 4 + 3] = z4.w;
    wn[d4 * 4 + 0] = n4.x; wn[d4 * 4 + 1] = n4.y; wn[d4 * 4 + 2] = n4.z; wn[d4 * 4 + 3] = n4.w;
  }
  float h = 0.f;
  for (int t = 0; t < T_; ++t) {
    const float xr = xw[t * G3_ + j];
    const float xz = xw[t * G3_ + 64 + j];
    const float xn = xw[t * G3_ + 128 + j];
    float ar = 0.f, az = 0.f, an = 0.f;
    const int hb = __float_as_int(h);
#pragma unroll
    for (int d = 0; d < 64; ++d) {
      const float hd = __int_as_float(__builtin_amdgcn_readlane(hb, d));
      ar += wr[d] * hd;
      az += wz[d] * hd;
      an += wn[d] * hd;
    }
    const float r = 1.f / (1.f + __expf(-(xr + ar)));
    const float z = 1.f / (1.f + __expf(-(xz + az)));
    const float pre = xn + r * an;
    const float ea = __expf(-2.f * fabsf(pre));
    float nn = (1.f - ea) / (1.f + ea);
    nn = copysignf(nn, pre);
    h = (1.f - z) * nn + z * h;
    a[(size_t)t * E_ + j] = (f16)h;
  }
}

// ---------------- GEMM: C[M][1024] = A[M][1024](f16) @ W[1024][1024]^T(f16) --
// MODE 0: + add[m][n] (residual x). MODE 1: + bias[n].
template <int MODE>
__global__ __launch_bounds__(256) void k_gemm(
    const f16* __restrict__ A, const f16* __restrict__ W,
    const float* __restrict__ add, const float* __restrict__ bias,
    float* __restrict__ C) {
  __shared__ __align__(16) f16 As[128][72];
  __shared__ __align__(16) f16 Bs[128][72];
  const int m0 = blockIdx.x * 128, n0 = blockIdx.y * 128;
  const int tid = threadIdx.x;
  const int wid = tid >> 6, lane = tid & 63;
  const int wr = wid >> 1, wc = wid & 1;
  const int lg = lane >> 4, lc = lane & 15;
  f32x4 acc[4][4] = {};
  for (int kt = 0; kt < E_; kt += 64) {
#pragma unroll
    for (int it = 0; it < 4; ++it) {
      const int r = it * 32 + (tid >> 3);
      const int cs = (tid & 7) * 8;
      *(f16x8*)&As[r][cs] = *(const f16x8*)(A + (size_t)(m0 + r) * E_ + kt + cs);
      *(f16x8*)&Bs[r][cs] = *(const f16x8*)(W + (size_t)(n0 + r) * E_ + kt + cs);
    }
    __syncthreads();
    f16x8 af[4][2], bf[4][2];
#pragma unroll
    for (int mi = 0; mi < 4; ++mi)
#pragma unroll
      for (int ks = 0; ks < 2; ++ks) {
        af[mi][ks] = *(const f16x8*)&As[wr * 64 + mi * 16 + lc][ks * 32 + lg * 8];
        bf[mi][ks] = *(const f16x8*)&Bs[wc * 64 + mi * 16 + lc][ks * 32 + lg * 8];
      }
#pragma unroll
    for (int mi = 0; mi < 4; ++mi)
#pragma unroll
      for (int ni = 0; ni < 4; ++ni)
#pragma unroll
        for (int ks = 0; ks < 2; ++ks)
          acc[mi][ni] = mfma16(af[mi][ks], bf[ni][ks], acc[mi][ni]);
    __syncthreads();
  }
#pragma unroll
  for (int mi = 0; mi < 4; ++mi) {
    const int r0 = m0 + wr * 64 + mi * 16 + lg * 4;
#pragma unroll
    for (int ni = 0; ni < 4; ++ni) {
      const int col = n0 + wc * 64 + ni * 16 + lc;
      const float bv = (MODE == 1) ? bias[col] : 0.f;
#pragma unroll
      for (int q = 0; q < 4; ++q) {
        float v = acc[mi][ni][q];
        if (MODE == 0) v += add[(size_t)(r0 + q) * E_ + col];
        else v += bv;
        C[(size_t)(r0 + q) * E_ + col] = v;
      }
    }
  }
}

// ---------------- LayerNorm row of 1024, write f16 in [B,H,T,HD] -----------
__global__ __launch_bounds__(256) void k_ln(const float* __restrict__ pre,
                                            const float* __restrict__ gw,
                                            const float* __restrict__ gb,
                                            f16* __restrict__ outp) {
  const int row = blockIdx.x;
  const int tid = threadIdx.x;
  const float4 v = ((const float4*)(pre + (size_t)row * E_))[tid];
  float s = v.x + v.y + v.z + v.w;
  float s2 = v.x * v.x + v.y * v.y + v.z * v.z + v.w * v.w;
#pragma unroll
  for (int off = 32; off; off >>= 1) {
    s += __shfl_xor(s, off);
    s2 += __shfl_xor(s2, off);
  }
  __shared__ float red[8];
  const int wid = tid >> 6, lane = tid & 63;
  if (!lane) { red[wid] = s; red[4 + wid] = s2; }
  __syncthreads();
  s = red[0] + red[1] + red[2] + red[3];
  s2 = red[4] + red[5] + red[6] + red[7];
  const float mu = s * (1.f / E_);
  const float inv = rsqrtf(s2 * (1.f / E_) - mu * mu + 1e-5f);
  const float4 w4 = ((const float4*)gw)[tid];
  const float4 b4 = ((const float4*)gb)[tid];
  const int e0 = tid * 4;
  f16x4 o;
  o[0] = (f16)((v.x - mu) * inv * w4.x + b4.x);
  o[1] = (f16)((v.y - mu) * inv * w4.y + b4.y);
  o[2] = (f16)((v.z - mu) * inv * w4.z + b4.z);
  o[3] = (f16)((v.w - mu) * inv * w4.w + b4.w);
  const int b = row >> 11, t = row & (T_ - 1);
  const size_t off2 = ((size_t)(b * H_ + (e0 >> 6)) * T_ + t) * HD_ + (e0 & 63);
  *(f16x4*)(outp + off2) = o;
}

// ---------------- flash attention: causal, scores*2/sqrt(64) = *0.25 -------
__global__ __launch_bounds__(256) void k_attn(const f16* __restrict__ Q,
                                              const f16* __restrict__ K,
                                              const f16* __restrict__ V,
                                              f16* __restrict__ AO) {
  __shared__ __align__(16) f16 Kt[64][72];
  __shared__ __align__(16) f16 Vt[64][72];  // transposed: Vt[d][kv]
  __shared__ __align__(16) f16 Ps[4][16][72];
  const int qi = blockIdx.x, bh = blockIdx.y;
  const int b = bh >> 4, h = bh & 15;
  const int tid = threadIdx.x, wid = tid >> 6, lane = tid & 63;
  const int lg = lane >> 4, lc = lane & 15;
  const size_t hbase = (size_t)bh * T_ * HD_;
  const int qb = qi * 64;
  f16x8 qf[2];
  {
    const int qrow = qb + wid * 16 + lc;
#pragma unroll
    for (int ks = 0; ks < 2; ++ks)
      qf[ks] = *(const f16x8*)(Q + hbase + (size_t)qrow * HD_ + ks * 32 + lg * 8);
  }
  f32x4 o[4] = {};
  float m_run[4] = {-1e30f, -1e30f, -1e30f, -1e30f};
  float l_run[4] = {};
  const int qrow_d = qb + wid * 16 + lg * 4;
  for (int kt = 0; kt <= qi; ++kt) {
    {
      const int r = tid >> 2, cs = (tid & 3) * 16;
      const f16* ksrc = K + hbase + (size_t)(kt * 64 + r) * HD_ + cs;
      *(f16x8*)&Kt[r][cs] = *(const f16x8*)ksrc;
      *(f16x8*)&Kt[r][cs + 8] = *(const f16x8*)(ksrc + 8);
      const f16* vsrc = V + hbase + (size_t)(kt * 64 + lane) * HD_ + wid * 16;
      f16x8 va = *(const f16x8*)vsrc;
      f16x8 vb = *(const f16x8*)(vsrc + 8);
#pragma unroll
      for (int u = 0; u < 8; ++u) {
        Vt[wid * 16 + u][lane] = va[u];
        Vt[wid * 16 + 8 + u][lane] = vb[u];
      }
    }
    __syncthreads();
    f32x4 s[4] = {};
#pragma unroll
    for (int nt = 0; nt < 4; ++nt)
#pragma unroll
      for (int ks = 0; ks < 2; ++ks) {
        f16x8 kf = *(const f16x8*)&Kt[nt * 16 + lc][ks * 32 + lg * 8];
        s[nt] = mfma16(qf[ks], kf, s[nt]);
      }
    const bool diag = (kt == qi);
#pragma unroll
    for (int nt = 0; nt < 4; ++nt) {
      const int colg = kt * 64 + nt * 16 + lc;
#pragma unroll
      for (int r = 0; r < 4; ++r) {
        float v = s[nt][r] * 0.25f;  // (qk/8)*2
        if (diag && colg > qrow_d + r) v = -1e30f;
        s[nt][r] = v;
      }
    }
    float scalev[4];
#pragma unroll
    for (int r = 0; r < 4; ++r) {
      float m = fmaxf(fmaxf(s[0][r], s[1][r]), fmaxf(s[2][r], s[3][r]));
#pragma unroll
      for (int of = 1; of < 16; of <<= 1) m = fmaxf(m, __shfl_xor(m, of));
      const float mn = fmaxf(m_run[r], m);
      scalev[r] = __expf(m_run[r] - mn);
      m_run[r] = mn;
    }
    float ladd[4] = {};
#pragma unroll
    for (int nt = 0; nt < 4; ++nt)
#pragma unroll
      for (int r = 0; r < 4; ++r) {
        const float p = __expf(s[nt][r] - m_run[r]);
        s[nt][r] = p;
        ladd[r] += p;
      }
#pragma unroll
    for (int r = 0; r < 4; ++r) {
      float la = ladd[r];
#pragma unroll
      for (int of = 1; of < 16; of <<= 1) la += __shfl_xor(la, of);
      l_run[r] = l_run[r] * scalev[r] + la;
      o[0][r] *= scalev[r];
      o[1][r] *= scalev[r];
      o[2][r] *= scalev[r];
      o[3][r] *= scalev[r];
    }
#pragma unroll
    for (int nt = 0; nt < 4; ++nt)
#pragma unroll
      for (int r = 0; r < 4; ++r)
        Ps[wid][lg * 4 + r][nt * 16 + lc] = (f16)s[nt][r];
    f16x8 pf[2];
#pragma unroll
    for (int ks = 0; ks < 2; ++ks)
      pf[ks] = *(const f16x8*)&Ps[wid][lc][ks * 32 + lg * 8];
#pragma unroll
    for (int nt = 0; nt < 4; ++nt)
#pragma unroll
      for (int ks = 0; ks < 2; ++ks) {
        f16x8 vf = *(const f16x8*)&Vt[nt * 16 + lc][ks * 32 + lg * 8];
        o[nt] = mfma16(pf[ks], vf, o[nt]);
      }
    __syncthreads();
  }
#pragma unroll
  for (int nt = 0; nt < 4; ++nt)
#pragma unroll
    for (int r = 0; r < 4; ++r) {
      const float val = o[nt][r] / l_run[r];
      const int qrow = qrow_d + r;
      AO[((size_t)(b * T_ + qrow)) * E_ + h * HD_ + nt * 16 + lc] = (f16)val;
    }
}

}  // namespace

extern "C" void kernel_launch(void* const* d_in, const int* in_sizes, int n_in,
                              void* d_out, int out_size, void* d_ws, size_t ws_size,
                              hipStream_t stream) {
  (void)in_sizes; (void)n_in; (void)out_size; (void)ws_size;
  const float* x      = (const float*)d_in[0];
  const int*   tok    = (const int*)d_in[1];
  const float* q_wih  = (const float*)d_in[2];
  const float* q_whh  = (const float*)d_in[3];
  const float* q_lin  = (const float*)d_in[4];
  const float* k_wih  = (const float*)d_in[5];
  const float* k_whh  = (const float*)d_in[6];
  const float* k_lin  = (const float*)d_in[7];
  const float* v_emb  = (const float*)d_in[8];
  const float* q_ln_w = (const float*)d_in[9];
  const float* q_ln_b = (const float*)d_in[10];
  const float* k_ln_w = (const float*)d_in[11];
  const float* k_ln_b = (const float*)d_in[12];
  const float* out_w  = (const float*)d_in[13];
  const float* out_b  = (const float*)d_in[14];
  float* outp = (float*)d_out;

  char* ws = (char*)d_ws;
  size_t off = 0;
  auto take = [&](size_t bytes) -> void* {
    void* p = ws + off;
    off += (bytes + 255) & ~(size_t)255;
    return p;
  };
  f16* WQ   = (f16*)take((size_t)E_ * E_ * 2);
  f16* WK   = (f16*)take((size_t)E_ * E_ * 2);
  f16* WO   = (f16*)take((size_t)E_ * E_ * 2);
  f16* WIHQ = (f16*)take((size_t)G3_ * 64 * 2);
  f16* WIHK = (f16*)take((size_t)G3_ * 64 * 2);
  f16* AQ   = (f16*)take((size_t)M_ * E_ * 2);
  f16* AK   = (f16*)take((size_t)M_ * E_ * 2);
  f16* VH   = (f16*)take((size_t)M_ * E_ * 2);
  f16* QH   = (f16*)take((size_t)M_ * E_ * 2);
  f16* KH   = (f16*)take((size_t)M_ * E_ * 2);
  f16* AO   = (f16*)take((size_t)M_ * E_ * 2);
  float* XWQ  = (float*)take((size_t)M_ * G3_ * 4);
  float* XWK  = (float*)take((size_t)M_ * G3_ * 4);
  float* QPRE = (float*)take((size_t)M_ * E_ * 4);
  float* KPRE = (float*)take((size_t)M_ * E_ * 4);

  k_cvt<<<dim3((E_ * E_) / 1024), dim3(256), 0, stream>>>(q_lin, WQ, E_ * E_);
  k_cvt<<<dim3((E_ * E_) / 1024), dim3(256), 0, stream>>>(k_lin, WK, E_ * E_);
  k_cvt<<<dim3((E_ * E_) / 1024), dim3(256), 0, stream>>>(out_w, WO, E_ * E_);
  k_cvt<<<dim3((G3_ * 64) / 1024), dim3(256), 0, stream>>>(q_wih, WIHQ, G3_ * 64);
  k_cvt<<<dim3((G3_ * 64) / 1024), dim3(256), 0, stream>>>(k_wih, WIHK, G3_ * 64);

  k_prep<<<dim3(M_), dim3(256), 0, stream>>>(x, tok, WIHQ, WIHK, v_emb, VH, AQ, AK, XWQ, XWK);
  k_gru<<<dim3(4), dim3(64), 0, stream>>>(XWQ, XWK, q_whh, k_whh, AQ, AK);

  k_gemm<0><<<dim3(M_ / 128, E_ / 128), dim3(256), 0, stream>>>(AQ, WQ, x, nullptr, QPRE);
  k_gemm<0><<<dim3(M_ / 128, E_ / 128), dim3(256), 0, stream>>>(AK, WK, x, nullptr, KPRE);
  k_ln<<<dim3(M_), dim3(256), 0, stream>>>(QPRE, q_ln_w, q_ln_b, QH);
  k_ln<<<dim3(M_), dim3(256), 0, stream>>>(KPRE, k_ln_w, k_ln_b, KH);

  k_attn<<<dim3(T_ / 64, B_ * H_), dim3(256), 0, stream>>>(QH, KH, VH, AO);
  k_gemm<1><<<dim3(M_ / 128, E_ / 128), dim3(256), 0, stream>>>(AO, WO, nullptr, out_b, outp);
}

// Round 2
// 1084.403 us; speedup vs baseline: 1.3852x; 1.3852x over previous
//
#include <hip/hip_runtime.h>

// R2: GRU inner loop rewritten: v_dot2_f32_f16 packed dot (96 dot2 vs 192 FMA),
// packed-pair readlane broadcast (32 vs 64), software-prefetched xw loads.
// h stays f32 in-lane; only the matvec operand is f16 (f32 accumulate).
// Rest of pipeline unchanged from R1 (passed, absmax 0.0078).

namespace {

constexpr int B_ = 2, T_ = 2048, E_ = 1024, H_ = 16, HD_ = 64, G3_ = 192, M_ = B_ * T_;

typedef _Float16 f16;
typedef _Float16 f16x8 __attribute__((ext_vector_type(8)));
typedef _Float16 f16x4 __attribute__((ext_vector_type(4)));
typedef _Float16 f16x2 __attribute__((ext_vector_type(2)));
typedef float f32x4 __attribute__((ext_vector_type(4)));

__device__ __forceinline__ f32x4 mfma16(f16x8 a, f16x8 b, f32x4 c) {
  return __builtin_amdgcn_mfma_f32_16x16x32_f16(a, b, c, 0, 0, 0);
}

#if __has_builtin(__builtin_amdgcn_fdot2)
__device__ __forceinline__ float fdot2(f16x2 a, f16x2 b, float c) {
  return __builtin_amdgcn_fdot2(a, b, c, false);
}
#else
__device__ __forceinline__ float fdot2(f16x2 a, f16x2 b, float c) {
  return c + (float)a[0] * (float)b[0] + (float)a[1] * (float)b[1];
}
#endif

// ---------------- fp32 -> fp16 convert ----------------
__global__ __launch_bounds__(256) void k_cvt(const float* __restrict__ s,
                                             f16* __restrict__ d, int n) {
  int i = (blockIdx.x * 256 + threadIdx.x) * 4;
  if (i < n) {
    float4 v = *(const float4*)(s + i);
    f16x4 o = {(f16)v.x, (f16)v.y, (f16)v.z, (f16)v.w};
    *(f16x4*)(d + i) = o;
  }
}

// ---------------- prep: v = silu(x)*emb, x_proj pooling, xw = pool16(x)@wih^T
__global__ __launch_bounds__(256) void k_prep(
    const float* __restrict__ x, const int* __restrict__ tok,
    const f16* __restrict__ wihq, const f16* __restrict__ wihk,
    const float* __restrict__ v_emb,
    f16* __restrict__ vh, f16* __restrict__ aq, f16* __restrict__ ak,
    float* __restrict__ xwq, float* __restrict__ xwk) {
  __shared__ float xs[E_];
  __shared__ float xp[64];
  const int row = blockIdx.x;
  const int b = row >> 11, t = row & (T_ - 1);
  const int tid = threadIdx.x;
  const float* xrow = x + (size_t)row * E_;
  {
    const int tk = tok[row];
    float4 xv = ((const float4*)xrow)[tid];
    ((float4*)xs)[tid] = xv;
    float4 ev = ((const float4*)(v_emb + (size_t)tk * E_))[tid];
    f16x4 o;
    o[0] = (f16)(xv.x / (1.f + __expf(-xv.x)) * ev.x);
    o[1] = (f16)(xv.y / (1.f + __expf(-xv.y)) * ev.y);
    o[2] = (f16)(xv.z / (1.f + __expf(-xv.z)) * ev.z);
    o[3] = (f16)(xv.w / (1.f + __expf(-xv.w)) * ev.w);
    const int e0 = tid * 4;
    const size_t voff = ((size_t)(b * H_ + (e0 >> 6)) * T_ + t) * HD_ + (e0 & 63);
    *(f16x4*)(vh + voff) = o;
  }
  __syncthreads();
  if (tid < 64) {
    float s = 0.f;
#pragma unroll
    for (int j = 0; j < 16; ++j) s += xs[tid * 16 + j];
    xp[tid] = s * (1.f / 16.f);
  }
  // adaptive pool 1024 -> 960 on feature dim (window 1 or 2)
  for (int i = tid; i < 960; i += 256) {
    int s0 = (i * 1024) / 960;
    int e0 = ((i + 1) * 1024 + 959) / 960;
    float m = xs[s0];
    if (e0 - s0 == 2) m = (m + xs[s0 + 1]) * 0.5f;
    f16 hv = (f16)m;
    aq[(size_t)row * E_ + 64 + i] = hv;
    ak[(size_t)row * E_ + 64 + i] = hv;
  }
  __syncthreads();
  // xw[g] = sum_d xp[d] * wih[g][d], for both chains
  for (int o = tid; o < 2 * G3_; o += 256) {
    const int chain = o / G3_, g = o % G3_;
    const f16* wrow = (chain ? wihk : wihq) + g * 64;
    float acc = 0.f;
#pragma unroll
    for (int c = 0; c < 8; ++c) {
      f16x8 wv = *(const f16x8*)(wrow + c * 8);
#pragma unroll
      for (int u = 0; u < 8; ++u) acc += xp[c * 8 + u] * (float)wv[u];
    }
    (chain ? xwk : xwq)[(size_t)row * G3_ + g] = acc;
  }
}

// ---------------- GRU: 4 independent chains (q/k x b0/b1), 1 wave each ------
// lane j holds h[j]; per step: pack h to f16 pairs, 32 packed readlane
// broadcasts, 96 v_dot2_f32_f16 (f32 accumulate), prefetched xw.
__global__ __launch_bounds__(64, 1) void k_gru(
    const float* __restrict__ xwq, const float* __restrict__ xwk,
    const float* __restrict__ whhq, const float* __restrict__ whhk,
    f16* __restrict__ aq, f16* __restrict__ ak) {
  const int blk = blockIdx.x;
  const int chain = blk >> 1, b = blk & 1;
  const float* xw = (chain ? xwk : xwq) + (size_t)b * T_ * G3_;
  const float* whh = chain ? whhk : whhq;
  f16* a = (chain ? ak : aq) + (size_t)b * T_ * E_;
  const int j = threadIdx.x;
  // preload whh rows for this lane's 3 outputs, packed to f16 pairs
  f16x2 wr2[32], wz2[32], wn2[32];
#pragma unroll
  for (int i = 0; i < 32; ++i) {
    float2 r2 = *(const float2*)(whh + (size_t)j * 64 + 2 * i);
    float2 z2 = *(const float2*)(whh + (size_t)(64 + j) * 64 + 2 * i);
    float2 n2 = *(const float2*)(whh + (size_t)(128 + j) * 64 + 2 * i);
    wr2[i] = {(f16)r2.x, (f16)r2.y};
    wz2[i] = {(f16)z2.x, (f16)z2.y};
    wn2[i] = {(f16)n2.x, (f16)n2.y};
  }
  float h = 0.f;
  float xr = xw[j], xz = xw[64 + j], xn = xw[128 + j];
  for (int t = 0; t < T_; ++t) {
    // pack (h_{2i}, h_{2i+1}) as f16x2 in even lanes, broadcast via readlane
    const f16 h16 = (f16)h;
    const unsigned hu = (unsigned)__builtin_bit_cast(unsigned short, h16);
    const unsigned nb = (unsigned)__shfl_xor((int)hu, 1) & 0xffffu;
    const unsigned pk = (j & 1) ? (nb | (hu << 16)) : (hu | (nb << 16));
    int hp[32];
#pragma unroll
    for (int i = 0; i < 32; ++i) hp[i] = __builtin_amdgcn_readlane((int)pk, 2 * i);
    // prefetch next step's xw (clamped; hides global latency under dots)
    const int tn = (t + 1 < T_) ? (t + 1) : (T_ - 1);
    const float* xp2 = xw + (size_t)tn * G3_;
    const float nxr = xp2[j], nxz = xp2[64 + j], nxn = xp2[128 + j];
    float ar = 0.f, az = 0.f, an = 0.f;
#pragma unroll
    for (int i = 0; i < 32; ++i) {
      const f16x2 hh = __builtin_bit_cast(f16x2, hp[i]);
      ar = fdot2(wr2[i], hh, ar);
      az = fdot2(wz2[i], hh, az);
      an = fdot2(wn2[i], hh, an);
    }
    const float r = 1.f / (1.f + __expf(-(xr + ar)));
    const float z = 1.f / (1.f + __expf(-(xz + az)));
    const float pre = xn + r * an;
    const float ea = __expf(-2.f * fabsf(pre));
    float nn = (1.f - ea) / (1.f + ea);
    nn = copysignf(nn, pre);
    h = (1.f - z) * nn + z * h;
    a[(size_t)t * E_ + j] = (f16)h;
    xr = nxr; xz = nxz; xn = nxn;
  }
}

// ---------------- GEMM: C[M][1024] = A[M][1024](f16) @ W[1024][1024]^T(f16) --
// MODE 0: + add[m][n] (residual x). MODE 1: + bias[n].
template <int MODE>
__global__ __launch_bounds__(256) void k_gemm(
    const f16* __restrict__ A, const f16* __restrict__ W,
    const float* __restrict__ add, const float* __restrict__ bias,
    float* __restrict__ C) {
  __shared__ __align__(16) f16 As[128][72];
  __shared__ __align__(16) f16 Bs[128][72];
  const int m0 = blockIdx.x * 128, n0 = blockIdx.y * 128;
  const int tid = threadIdx.x;
  const int wid = tid >> 6, lane = tid & 63;
  const int wr = wid >> 1, wc = wid & 1;
  const int lg = lane >> 4, lc = lane & 15;
  f32x4 acc[4][4] = {};
  for (int kt = 0; kt < E_; kt += 64) {
#pragma unroll
    for (int it = 0; it < 4; ++it) {
      const int r = it * 32 + (tid >> 3);
      const int cs = (tid & 7) * 8;
      *(f16x8*)&As[r][cs] = *(const f16x8*)(A + (size_t)(m0 + r) * E_ + kt + cs);
      *(f16x8*)&Bs[r][cs] = *(const f16x8*)(W + (size_t)(n0 + r) * E_ + kt + cs);
    }
    __syncthreads();
    f16x8 af[4][2], bf[4][2];
#pragma unroll
    for (int mi = 0; mi < 4; ++mi)
#pragma unroll
      for (int ks = 0; ks < 2; ++ks) {
        af[mi][ks] = *(const f16x8*)&As[wr * 64 + mi * 16 + lc][ks * 32 + lg * 8];
        bf[mi][ks] = *(const f16x8*)&Bs[wc * 64 + mi * 16 + lc][ks * 32 + lg * 8];
      }
#pragma unroll
    for (int mi = 0; mi < 4; ++mi)
#pragma unroll
      for (int ni = 0; ni < 4; ++ni)
#pragma unroll
        for (int ks = 0; ks < 2; ++ks)
          acc[mi][ni] = mfma16(af[mi][ks], bf[ni][ks], acc[mi][ni]);
    __syncthreads();
  }
#pragma unroll
  for (int mi = 0; mi < 4; ++mi) {
    const int r0 = m0 + wr * 64 + mi * 16 + lg * 4;
#pragma unroll
    for (int ni = 0; ni < 4; ++ni) {
      const int col = n0 + wc * 64 + ni * 16 + lc;
      const float bv = (MODE == 1) ? bias[col] : 0.f;
#pragma unroll
      for (int q = 0; q < 4; ++q) {
        float v = acc[mi][ni][q];
        if (MODE == 0) v += add[(size_t)(r0 + q) * E_ + col];
        else v += bv;
        C[(size_t)(r0 + q) * E_ + col] = v;
      }
    }
  }
}

// ---------------- LayerNorm row of 1024, write f16 in [B,H,T,HD] -----------
__global__ __launch_bounds__(256) void k_ln(const float* __restrict__ pre,
                                            const float* __restrict__ gw,
                                            const float* __restrict__ gb,
                                            f16* __restrict__ outp) {
  const int row = blockIdx.x;
  const int tid = threadIdx.x;
  const float4 v = ((const float4*)(pre + (size_t)row * E_))[tid];
  float s = v.x + v.y + v.z + v.w;
  float s2 = v.x * v.x + v.y * v.y + v.z * v.z + v.w * v.w;
#pragma unroll
  for (int off = 32; off; off >>= 1) {
    s += __shfl_xor(s, off);
    s2 += __shfl_xor(s2, off);
  }
  __shared__ float red[8];
  const int wid = tid >> 6, lane = tid & 63;
  if (!lane) { red[wid] = s; red[4 + wid] = s2; }
  __syncthreads();
  s = red[0] + red[1] + red[2] + red[3];
  s2 = red[4] + red[5] + red[6] + red[7];
  const float mu = s * (1.f / E_);
  const float inv = rsqrtf(s2 * (1.f / E_) - mu * mu + 1e-5f);
  const float4 w4 = ((const float4*)gw)[tid];
  const float4 b4 = ((const float4*)gb)[tid];
  const int e0 = tid * 4;
  f16x4 o;
  o[0] = (f16)((v.x - mu) * inv * w4.x + b4.x);
  o[1] = (f16)((v.y - mu) * inv * w4.y + b4.y);
  o[2] = (f16)((v.z - mu) * inv * w4.z + b4.z);
  o[3] = (f16)((v.w - mu) * inv * w4.w + b4.w);
  const int b = row >> 11, t = row & (T_ - 1);
  const size_t off2 = ((size_t)(b * H_ + (e0 >> 6)) * T_ + t) * HD_ + (e0 & 63);
  *(f16x4*)(outp + off2) = o;
}

// ---------------- flash attention: causal, scores*2/sqrt(64) = *0.25 -------
__global__ __launch_bounds__(256) void k_attn(const f16* __restrict__ Q,
                                              const f16* __restrict__ K,
                                              const f16* __restrict__ V,
                                              f16* __restrict__ AO) {
  __shared__ __align__(16) f16 Kt[64][72];
  __shared__ __align__(16) f16 Vt[64][72];  // transposed: Vt[d][kv]
  __shared__ __align__(16) f16 Ps[4][16][72];
  const int qi = blockIdx.x, bh = blockIdx.y;
  const int b = bh >> 4, h = bh & 15;
  const int tid = threadIdx.x, wid = tid >> 6, lane = tid & 63;
  const int lg = lane >> 4, lc = lane & 15;
  const size_t hbase = (size_t)bh * T_ * HD_;
  const int qb = qi * 64;
  f16x8 qf[2];
  {
    const int qrow = qb + wid * 16 + lc;
#pragma unroll
    for (int ks = 0; ks < 2; ++ks)
      qf[ks] = *(const f16x8*)(Q + hbase + (size_t)qrow * HD_ + ks * 32 + lg * 8);
  }
  f32x4 o[4] = {};
  float m_run[4] = {-1e30f, -1e30f, -1e30f, -1e30f};
  float l_run[4] = {};
  const int qrow_d = qb + wid * 16 + lg * 4;
  for (int kt = 0; kt <= qi; ++kt) {
    {
      const int r = tid >> 2, cs = (tid & 3) * 16;
      const f16* ksrc = K + hbase + (size_t)(kt * 64 + r) * HD_ + cs;
      *(f16x8*)&Kt[r][cs] = *(const f16x8*)ksrc;
      *(f16x8*)&Kt[r][cs + 8] = *(const f16x8*)(ksrc + 8);
      const f16* vsrc = V + hbase + (size_t)(kt * 64 + lane) * HD_ + wid * 16;
      f16x8 va = *(const f16x8*)vsrc;
      f16x8 vb = *(const f16x8*)(vsrc + 8);
#pragma unroll
      for (int u = 0; u < 8; ++u) {
        Vt[wid * 16 + u][lane] = va[u];
        Vt[wid * 16 + 8 + u][lane] = vb[u];
      }
    }
    __syncthreads();
    f32x4 s[4] = {};
#pragma unroll
    for (int nt = 0; nt < 4; ++nt)
#pragma unroll
      for (int ks = 0; ks < 2; ++ks) {
        f16x8 kf = *(const f16x8*)&Kt[nt * 16 + lc][ks * 32 + lg * 8];
        s[nt] = mfma16(qf[ks], kf, s[nt]);
      }
    const bool diag = (kt == qi);
#pragma unroll
    for (int nt = 0; nt < 4; ++nt) {
      const int colg = kt * 64 + nt * 16 + lc;
#pragma unroll
      for (int r = 0; r < 4; ++r) {
        float v = s[nt][r] * 0.25f;  // (qk/8)*2
        if (diag && colg > qrow_d + r) v = -1e30f;
        s[nt][r] = v;
      }
    }
    float scalev[4];
#pragma unroll
    for (int r = 0; r < 4; ++r) {
      float m = fmaxf(fmaxf(s[0][r], s[1][r]), fmaxf(s[2][r], s[3][r]));
#pragma unroll
      for (int of = 1; of < 16; of <<= 1) m = fmaxf(m, __shfl_xor(m, of));
      const float mn = fmaxf(m_run[r], m);
      scalev[r] = __expf(m_run[r] - mn);
      m_run[r] = mn;
    }
    float ladd[4] = {};
#pragma unroll
    for (int nt = 0; nt < 4; ++nt)
#pragma unroll
      for (int r = 0; r < 4; ++r) {
        const float p = __expf(s[nt][r] - m_run[r]);
        s[nt][r] = p;
        ladd[r] += p;
      }
#pragma unroll
    for (int r = 0; r < 4; ++r) {
      float la = ladd[r];
#pragma unroll
      for (int of = 1; of < 16; of <<= 1) la += __shfl_xor(la, of);
      l_run[r] = l_run[r] * scalev[r] + la;
      o[0][r] *= scalev[r];
      o[1][r] *= scalev[r];
      o[2][r] *= scalev[r];
      o[3][r] *= scalev[r];
    }
#pragma unroll
    for (int nt = 0; nt < 4; ++nt)
#pragma unroll
      for (int r = 0; r < 4; ++r)
        Ps[wid][lg * 4 + r][nt * 16 + lc] = (f16)s[nt][r];
    f16x8 pf[2];
#pragma unroll
    for (int ks = 0; ks < 2; ++ks)
      pf[ks] = *(const f16x8*)&Ps[wid][lc][ks * 32 + lg * 8];
#pragma unroll
    for (int nt = 0; nt < 4; ++nt)
#pragma unroll
      for (int ks = 0; ks < 2; ++ks) {
        f16x8 vf = *(const f16x8*)&Vt[nt * 16 + lc][ks * 32 + lg * 8];
        o[nt] = mfma16(pf[ks], vf, o[nt]);
      }
    __syncthreads();
  }
#pragma unroll
  for (int nt = 0; nt < 4; ++nt)
#pragma unroll
    for (int r = 0; r < 4; ++r) {
      const float val = o[nt][r] / l_run[r];
      const int qrow = qrow_d + r;
      AO[((size_t)(b * T_ + qrow)) * E_ + h * HD_ + nt * 16 + lc] = (f16)val;
    }
}

}  // namespace

extern "C" void kernel_launch(void* const* d_in, const int* in_sizes, int n_in,
                              void* d_out, int out_size, void* d_ws, size_t ws_size,
                              hipStream_t stream) {
  (void)in_sizes; (void)n_in; (void)out_size; (void)ws_size;
  const float* x      = (const float*)d_in[0];
  const int*   tok    = (const int*)d_in[1];
  const float* q_wih  = (const float*)d_in[2];
  const float* q_whh  = (const float*)d_in[3];
  const float* q_lin  = (const float*)d_in[4];
  const float* k_wih  = (const float*)d_in[5];
  const float* k_whh  = (const float*)d_in[6];
  const float* k_lin  = (const float*)d_in[7];
  const float* v_emb  = (const float*)d_in[8];
  const float* q_ln_w = (const float*)d_in[9];
  const float* q_ln_b = (const float*)d_in[10];
  const float* k_ln_w = (const float*)d_in[11];
  const float* k_ln_b = (const float*)d_in[12];
  const float* out_w  = (const float*)d_in[13];
  const float* out_b  = (const float*)d_in[14];
  float* outp = (float*)d_out;

  char* ws = (char*)d_ws;
  size_t off = 0;
  auto take = [&](size_t bytes) -> void* {
    void* p = ws + off;
    off += (bytes + 255) & ~(size_t)255;
    return p;
  };
  f16* WQ   = (f16*)take((size_t)E_ * E_ * 2);
  f16* WK   = (f16*)take((size_t)E_ * E_ * 2);
  f16* WO   = (f16*)take((size_t)E_ * E_ * 2);
  f16* WIHQ = (f16*)take((size_t)G3_ * 64 * 2);
  f16* WIHK = (f16*)take((size_t)G3_ * 64 * 2);
  f16* AQ   = (f16*)take((size_t)M_ * E_ * 2);
  f16* AK   = (f16*)take((size_t)M_ * E_ * 2);
  f16* VH   = (f16*)take((size_t)M_ * E_ * 2);
  f16* QH   = (f16*)take((size_t)M_ * E_ * 2);
  f16* KH   = (f16*)take((size_t)M_ * E_ * 2);
  f16* AO   = (f16*)take((size_t)M_ * E_ * 2);
  float* XWQ  = (float*)take((size_t)M_ * G3_ * 4);
  float* XWK  = (float*)take((size_t)M_ * G3_ * 4);
  float* QPRE = (float*)take((size_t)M_ * E_ * 4);
  float* KPRE = (float*)take((size_t)M_ * E_ * 4);

  k_cvt<<<dim3((E_ * E_) / 1024), dim3(256), 0, stream>>>(q_lin, WQ, E_ * E_);
  k_cvt<<<dim3((E_ * E_) / 1024), dim3(256), 0, stream>>>(k_lin, WK, E_ * E_);
  k_cvt<<<dim3((E_ * E_) / 1024), dim3(256), 0, stream>>>(out_w, WO, E_ * E_);
  k_cvt<<<dim3((G3_ * 64) / 1024), dim3(256), 0, stream>>>(q_wih, WIHQ, G3_ * 64);
  k_cvt<<<dim3((G3_ * 64) / 1024), dim3(256), 0, stream>>>(k_wih, WIHK, G3_ * 64);

  k_prep<<<dim3(M_), dim3(256), 0, stream>>>(x, tok, WIHQ, WIHK, v_emb, VH, AQ, AK, XWQ, XWK);
  k_gru<<<dim3(4), dim3(64), 0, stream>>>(XWQ, XWK, q_whh, k_whh, AQ, AK);

  k_gemm<0><<<dim3(M_ / 128, E_ / 128), dim3(256), 0, stream>>>(AQ, WQ, x, nullptr, QPRE);
  k_gemm<0><<<dim3(M_ / 128, E_ / 128), dim3(256), 0, stream>>>(AK, WK, x, nullptr, KPRE);
  k_ln<<<dim3(M_), dim3(256), 0, stream>>>(QPRE, q_ln_w, q_ln_b, QH);
  k_ln<<<dim3(M_), dim3(256), 0, stream>>>(KPRE, k_ln_w, k_ln_b, KH);

  k_attn<<<dim3(T_ / 64, B_ * H_), dim3(256), 0, stream>>>(QH, KH, VH, AO);
  k_gemm<1><<<dim3(M_ / 128, E_ / 128), dim3(256), 0, stream>>>(AO, WO, nullptr, out_b, outp);
}

// Round 3
// 883.776 us; speedup vs baseline: 1.6997x; 1.2270x over previous
//
#include <hip/hip_runtime.h>

// R3: (1) GRU: permlane32_swap pair-pack (no LDS shuffle), exp2-folded gates
//     (scales baked into whh at preload and xw in k_prep), r->n->z dot order.
// (2) Megakernel: GRU block 0 + Q/K partial GEMMs (K=64..1023) + WO cvt run
//     concurrently; k_fix adds the rank-64 GRU term + residual afterwards.

namespace {

constexpr int B_ = 2, T_ = 2048, E_ = 1024, H_ = 16, HD_ = 64, G3_ = 192, M_ = B_ * T_;
constexpr float SRg = -1.4426950408889634f;  // -log2(e), r/z gates
constexpr float SNg = 2.8853900817779268f;   // 2*log2(e), n gate

typedef _Float16 f16;
typedef _Float16 f16x8 __attribute__((ext_vector_type(8)));
typedef _Float16 f16x4 __attribute__((ext_vector_type(4)));
typedef _Float16 f16x2 __attribute__((ext_vector_type(2)));
typedef float f32x4 __attribute__((ext_vector_type(4)));

__device__ __forceinline__ f32x4 mfma16(f16x8 a, f16x8 b, f32x4 c) {
  return __builtin_amdgcn_mfma_f32_16x16x32_f16(a, b, c, 0, 0, 0);
}

#if __has_builtin(__builtin_amdgcn_fdot2)
__device__ __forceinline__ float fdot2(f16x2 a, f16x2 b, float c) {
  return __builtin_amdgcn_fdot2(a, b, c, false);
}
#else
__device__ __forceinline__ float fdot2(f16x2 a, f16x2 b, float c) {
  return c + (float)a[0] * (float)b[0] + (float)a[1] * (float)b[1];
}
#endif

__device__ __forceinline__ float exp2_(float x) {
#if __has_builtin(__builtin_amdgcn_exp2f)
  return __builtin_amdgcn_exp2f(x);
#else
  return exp2f(x);
#endif
}
__device__ __forceinline__ float rcp_(float x) {
#if __has_builtin(__builtin_amdgcn_rcpf)
  return __builtin_amdgcn_rcpf(x);
#else
  return 1.f / x;
#endif
}

// ---------------- fp32 -> fp16 convert ----------------
__global__ __launch_bounds__(256) void k_cvt(const float* __restrict__ s,
                                             f16* __restrict__ d, int n) {
  int i = (blockIdx.x * 256 + threadIdx.x) * 4;
  if (i < n) {
    float4 v = *(const float4*)(s + i);
    f16x4 o = {(f16)v.x, (f16)v.y, (f16)v.z, (f16)v.w};
    *(f16x4*)(d + i) = o;
  }
}

// ---------------- prep: v = silu(x)*emb, x_proj pooling, xw = pool16(x)@wih^T
// xw written PRE-SCALED for exp2-based gates.
__global__ __launch_bounds__(256) void k_prep(
    const float* __restrict__ x, const int* __restrict__ tok,
    const f16* __restrict__ wihq, const f16* __restrict__ wihk,
    const float* __restrict__ v_emb,
    f16* __restrict__ vh, f16* __restrict__ aq, f16* __restrict__ ak,
    float* __restrict__ xwq, float* __restrict__ xwk) {
  __shared__ float xs[E_];
  __shared__ float xp[64];
  const int row = blockIdx.x;
  const int b = row >> 11, t = row & (T_ - 1);
  const int tid = threadIdx.x;
  const float* xrow = x + (size_t)row * E_;
  {
    const int tk = tok[row];
    float4 xv = ((const float4*)xrow)[tid];
    ((float4*)xs)[tid] = xv;
    float4 ev = ((const float4*)(v_emb + (size_t)tk * E_))[tid];
    f16x4 o;
    o[0] = (f16)(xv.x / (1.f + __expf(-xv.x)) * ev.x);
    o[1] = (f16)(xv.y / (1.f + __expf(-xv.y)) * ev.y);
    o[2] = (f16)(xv.z / (1.f + __expf(-xv.z)) * ev.z);
    o[3] = (f16)(xv.w / (1.f + __expf(-xv.w)) * ev.w);
    const int e0 = tid * 4;
    const size_t voff = ((size_t)(b * H_ + (e0 >> 6)) * T_ + t) * HD_ + (e0 & 63);
    *(f16x4*)(vh + voff) = o;
  }
  __syncthreads();
  if (tid < 64) {
    float s = 0.f;
#pragma unroll
    for (int j = 0; j < 16; ++j) s += xs[tid * 16 + j];
    xp[tid] = s * (1.f / 16.f);
  }
  for (int i = tid; i < 960; i += 256) {
    int s0 = (i * 1024) / 960;
    int e0 = ((i + 1) * 1024 + 959) / 960;
    float m = xs[s0];
    if (e0 - s0 == 2) m = (m + xs[s0 + 1]) * 0.5f;
    f16 hv = (f16)m;
    aq[(size_t)row * E_ + 64 + i] = hv;
    ak[(size_t)row * E_ + 64 + i] = hv;
  }
  __syncthreads();
  for (int o = tid; o < 2 * G3_; o += 256) {
    const int chain = o / G3_, g = o % G3_;
    const f16* wrow = (chain ? wihk : wihq) + g * 64;
    float acc = 0.f;
#pragma unroll
    for (int c = 0; c < 8; ++c) {
      f16x8 wv = *(const f16x8*)(wrow + c * 8);
#pragma unroll
      for (int u = 0; u < 8; ++u) acc += xp[c * 8 + u] * (float)wv[u];
    }
    const float sc = (g < 128) ? SRg : SNg;
    (chain ? xwk : xwq)[(size_t)row * G3_ + g] = acc * sc;
  }
}

// ---------------- GRU core: one wave, lane j owns h_j -----------------------
// pairs over K are (k, k+32); h-pair formed via v_permlane32_swap_b32 (VALU).
__device__ __forceinline__ void gru_core(const float* __restrict__ xw,
                                         const float* __restrict__ whh,
                                         f16* __restrict__ a, int lane) {
  f16x2 wr[32], wz[32], wn[32];
#pragma unroll
  for (int i = 0; i < 32; ++i) {
    wr[i] = {(f16)(whh[(size_t)lane * 64 + i] * SRg),
             (f16)(whh[(size_t)lane * 64 + i + 32] * SRg)};
    wz[i] = {(f16)(whh[(size_t)(64 + lane) * 64 + i] * SRg),
             (f16)(whh[(size_t)(64 + lane) * 64 + i + 32] * SRg)};
    wn[i] = {(f16)(whh[(size_t)(128 + lane) * 64 + i] * SNg),
             (f16)(whh[(size_t)(128 + lane) * 64 + i + 32] * SNg)};
  }
  float h = 0.f;
  float xr = xw[lane], xz = xw[64 + lane], xn = xw[128 + lane];
  for (int t = 0; t < T_; ++t) {
    // pack pair (h_l, h_{l+32}) into lanes l<32 via permlane32_swap
    const unsigned hu = (unsigned)__builtin_bit_cast(unsigned short, (f16)h);
    int va = (int)hu, vb = (int)hu;
    asm volatile("v_permlane32_swap_b32 %0, %1" : "+v"(va), "+v"(vb));
    const int pk = (int)(hu | ((unsigned)va << 16));
    int hp[32];
#pragma unroll
    for (int i = 0; i < 32; ++i) hp[i] = __builtin_amdgcn_readlane(pk, i);
    // prefetch next step's (pre-scaled) xw
    const int tn = (t + 1 < T_) ? t + 1 : t;
    const float* nx = xw + (size_t)tn * G3_;
    const float nxr = nx[lane], nxz = nx[64 + lane], nxn = nx[128 + lane];
    // r gate first (its exp hides under n dots)
    float ar = xr;
#pragma unroll
    for (int i = 0; i < 32; ++i)
      ar = fdot2(wr[i], __builtin_bit_cast(f16x2, hp[i]), ar);
    const float r = rcp_(1.f + exp2_(ar));
    float an = 0.f;
#pragma unroll
    for (int i = 0; i < 32; ++i)
      an = fdot2(wn[i], __builtin_bit_cast(f16x2, hp[i]), an);
    const float p2 = fmaf(r, an, xn);              // = 2*log2e*(xn + r*hwn)
    const float n = fmaf(-2.f, rcp_(1.f + exp2_(p2)), 1.f);  // tanh
    float az = xz;
#pragma unroll
    for (int i = 0; i < 32; ++i)
      az = fdot2(wz[i], __builtin_bit_cast(f16x2, hp[i]), az);
    const float z = rcp_(1.f + exp2_(az));
    h = fmaf(z, h - n, n);
    a[(size_t)t * E_ + lane] = (f16)h;
    xr = nxr; xz = nxz; xn = nxn;
  }
}

// ---------------- megakernel: GRU (block 0) + QK partial GEMMs + WO cvt -----
__global__ __launch_bounds__(256, 1) void k_mega(
    const float* __restrict__ xwq, const float* __restrict__ xwk,
    const float* __restrict__ whhq, const float* __restrict__ whhk,
    f16* __restrict__ aq, f16* __restrict__ ak,
    const f16* __restrict__ WQ, const f16* __restrict__ WK,
    float* __restrict__ QPRE, float* __restrict__ KPRE,
    const float* __restrict__ out_w, f16* __restrict__ WO) {
  __shared__ __align__(16) f16 As[128][72];
  __shared__ __align__(16) f16 Bs[128][72];
  const int bx = blockIdx.x;
  const int tid = threadIdx.x;
  if (bx == 0) {
    const int wid = tid >> 6, lane = tid & 63;
    const int qk = wid >> 1, b = wid & 1;
    const float* xw = (qk ? xwk : xwq) + (size_t)b * T_ * G3_;
    const float* whh = qk ? whhk : whhq;
    f16* a = (qk ? ak : aq) + (size_t)b * T_ * E_;
    gru_core(xw, whh, a, lane);
    return;
  }
  if (bx <= 512) {
    // partial GEMM: C = A[:,64:1024] @ W[:,64:1024]^T
    const int bid = bx - 1;
    const int chain = bid >> 8, tile = bid & 255;
    const int m0 = (tile >> 3) * 128, n0 = (tile & 7) * 128;
    const f16* A = chain ? ak : aq;
    const f16* W = chain ? WK : WQ;
    float* C = chain ? KPRE : QPRE;
    const int wid = tid >> 6, lane = tid & 63;
    const int wr = wid >> 1, wc = wid & 1;
    const int lg = lane >> 4, lc = lane & 15;
    f32x4 acc[4][4] = {};
    for (int kt = 64; kt < E_; kt += 64) {
#pragma unroll
      for (int it = 0; it < 4; ++it) {
        const int r = it * 32 + (tid >> 3);
        const int cs = (tid & 7) * 8;
        *(f16x8*)&As[r][cs] = *(const f16x8*)(A + (size_t)(m0 + r) * E_ + kt + cs);
        *(f16x8*)&Bs[r][cs] = *(const f16x8*)(W + (size_t)(n0 + r) * E_ + kt + cs);
      }
      __syncthreads();
      f16x8 af[4][2], bf[4][2];
#pragma unroll
      for (int mi = 0; mi < 4; ++mi)
#pragma unroll
        for (int ks = 0; ks < 2; ++ks) {
          af[mi][ks] = *(const f16x8*)&As[wr * 64 + mi * 16 + lc][ks * 32 + lg * 8];
          bf[mi][ks] = *(const f16x8*)&Bs[wc * 64 + mi * 16 + lc][ks * 32 + lg * 8];
        }
#pragma unroll
      for (int mi = 0; mi < 4; ++mi)
#pragma unroll
        for (int ni = 0; ni < 4; ++ni)
#pragma unroll
          for (int ks = 0; ks < 2; ++ks)
            acc[mi][ni] = mfma16(af[mi][ks], bf[ni][ks], acc[mi][ni]);
      __syncthreads();
    }
#pragma unroll
    for (int mi = 0; mi < 4; ++mi) {
      const int r0 = m0 + wr * 64 + mi * 16 + lg * 4;
#pragma unroll
      for (int ni = 0; ni < 4; ++ni) {
        const int col = n0 + wc * 64 + ni * 16 + lc;
#pragma unroll
        for (int q = 0; q < 4; ++q)
          C[(size_t)(r0 + q) * E_ + col] = acc[mi][ni][q];
      }
    }
    return;
  }
  // WO convert (8 blocks, grid-stride)
  {
    const int cb = bx - 513;
    for (int i = cb * 256 + tid; i < E_ * E_ / 4; i += 8 * 256) {
      float4 v = ((const float4*)out_w)[i];
      f16x4 o = {(f16)v.x, (f16)v.y, (f16)v.z, (f16)v.w};
      *(f16x4*)(WO + (size_t)i * 4) = o;
    }
  }
}

// ---------------- fix: C += A[:,0:64] @ W[:,0:64]^T + x (residual) ----------
__global__ __launch_bounds__(256) void k_fix(
    const f16* __restrict__ aq, const f16* __restrict__ ak,
    const f16* __restrict__ WQ, const f16* __restrict__ WK,
    const float* __restrict__ x, float* __restrict__ QPRE,
    float* __restrict__ KPRE) {
  __shared__ __align__(16) f16 As[128][72];
  __shared__ __align__(16) f16 Bs[128][72];
  const int chain = blockIdx.z;
  const f16* A = chain ? ak : aq;
  const f16* W = chain ? WK : WQ;
  float* C = chain ? KPRE : QPRE;
  const int m0 = blockIdx.x * 128, n0 = blockIdx.y * 128;
  const int tid = threadIdx.x;
  const int wid = tid >> 6, lane = tid & 63;
  const int wr = wid >> 1, wc = wid & 1;
  const int lg = lane >> 4, lc = lane & 15;
#pragma unroll
  for (int it = 0; it < 4; ++it) {
    const int r = it * 32 + (tid >> 3);
    const int cs = (tid & 7) * 8;
    *(f16x8*)&As[r][cs] = *(const f16x8*)(A + (size_t)(m0 + r) * E_ + cs);
    *(f16x8*)&Bs[r][cs] = *(const f16x8*)(W + (size_t)(n0 + r) * E_ + cs);
  }
  __syncthreads();
  f32x4 acc[4][4] = {};
  f16x8 af[4][2], bf[4][2];
#pragma unroll
  for (int mi = 0; mi < 4; ++mi)
#pragma unroll
    for (int ks = 0; ks < 2; ++ks) {
      af[mi][ks] = *(const f16x8*)&As[wr * 64 + mi * 16 + lc][ks * 32 + lg * 8];
      bf[mi][ks] = *(const f16x8*)&Bs[wc * 64 + mi * 16 + lc][ks * 32 + lg * 8];
    }
#pragma unroll
  for (int mi = 0; mi < 4; ++mi)
#pragma unroll
    for (int ni = 0; ni < 4; ++ni)
#pragma unroll
      for (int ks = 0; ks < 2; ++ks)
        acc[mi][ni] = mfma16(af[mi][ks], bf[ni][ks], acc[mi][ni]);
#pragma unroll
  for (int mi = 0; mi < 4; ++mi) {
    const int r0 = m0 + wr * 64 + mi * 16 + lg * 4;
#pragma unroll
    for (int ni = 0; ni < 4; ++ni) {
      const int col = n0 + wc * 64 + ni * 16 + lc;
#pragma unroll
      for (int q = 0; q < 4; ++q) {
        const size_t idx = (size_t)(r0 + q) * E_ + col;
        C[idx] += acc[mi][ni][q] + x[idx];
      }
    }
  }
}

// ---------------- LayerNorm (both chains), write f16 in [B,H,T,HD] ---------
__global__ __launch_bounds__(256) void k_ln(
    const float* __restrict__ qpre, const float* __restrict__ kpre,
    const float* __restrict__ qw, const float* __restrict__ qb,
    const float* __restrict__ kw, const float* __restrict__ kb,
    f16* __restrict__ qh, f16* __restrict__ kh) {
  const int chain = blockIdx.y;
  const float* pre = chain ? kpre : qpre;
  const float* gw = chain ? kw : qw;
  const float* gb = chain ? kb : qb;
  f16* outp = chain ? kh : qh;
  const int row = blockIdx.x;
  const int tid = threadIdx.x;
  const float4 v = ((const float4*)(pre + (size_t)row * E_))[tid];
  float s = v.x + v.y + v.z + v.w;
  float s2 = v.x * v.x + v.y * v.y + v.z * v.z + v.w * v.w;
#pragma unroll
  for (int off = 32; off; off >>= 1) {
    s += __shfl_xor(s, off);
    s2 += __shfl_xor(s2, off);
  }
  __shared__ float red[8];
  const int wid = tid >> 6, lane = tid & 63;
  if (!lane) { red[wid] = s; red[4 + wid] = s2; }
  __syncthreads();
  s = red[0] + red[1] + red[2] + red[3];
  s2 = red[4] + red[5] + red[6] + red[7];
  const float mu = s * (1.f / E_);
  const float inv = rsqrtf(s2 * (1.f / E_) - mu * mu + 1e-5f);
  const float4 w4 = ((const float4*)gw)[tid];
  const float4 b4 = ((const float4*)gb)[tid];
  const int e0 = tid * 4;
  f16x4 o;
  o[0] = (f16)((v.x - mu) * inv * w4.x + b4.x);
  o[1] = (f16)((v.y - mu) * inv * w4.y + b4.y);
  o[2] = (f16)((v.z - mu) * inv * w4.z + b4.z);
  o[3] = (f16)((v.w - mu) * inv * w4.w + b4.w);
  const int b = row >> 11, t = row & (T_ - 1);
  const size_t off2 = ((size_t)(b * H_ + (e0 >> 6)) * T_ + t) * HD_ + (e0 & 63);
  *(f16x4*)(outp + off2) = o;
}

// ---------------- flash attention: causal, scores*2/sqrt(64) = *0.25 -------
__global__ __launch_bounds__(256) void k_attn(const f16* __restrict__ Q,
                                              const f16* __restrict__ K,
                                              const f16* __restrict__ V,
                                              f16* __restrict__ AO) {
  __shared__ __align__(16) f16 Kt[64][72];
  __shared__ __align__(16) f16 Vt[64][72];
  __shared__ __align__(16) f16 Ps[4][16][72];
  const int qi = blockIdx.x, bh = blockIdx.y;
  const int b = bh >> 4, h = bh & 15;
  const int tid = threadIdx.x, wid = tid >> 6, lane = tid & 63;
  const int lg = lane >> 4, lc = lane & 15;
  const size_t hbase = (size_t)bh * T_ * HD_;
  const int qb = qi * 64;
  f16x8 qf[2];
  {
    const int qrow = qb + wid * 16 + lc;
#pragma unroll
    for (int ks = 0; ks < 2; ++ks)
      qf[ks] = *(const f16x8*)(Q + hbase + (size_t)qrow * HD_ + ks * 32 + lg * 8);
  }
  f32x4 o[4] = {};
  float m_run[4] = {-1e30f, -1e30f, -1e30f, -1e30f};
  float l_run[4] = {};
  const int qrow_d = qb + wid * 16 + lg * 4;
  for (int kt = 0; kt <= qi; ++kt) {
    {
      const int r = tid >> 2, cs = (tid & 3) * 16;
      const f16* ksrc = K + hbase + (size_t)(kt * 64 + r) * HD_ + cs;
      *(f16x8*)&Kt[r][cs] = *(const f16x8*)ksrc;
      *(f16x8*)&Kt[r][cs + 8] = *(const f16x8*)(ksrc + 8);
      const f16* vsrc = V + hbase + (size_t)(kt * 64 + lane) * HD_ + wid * 16;
      f16x8 va = *(const f16x8*)vsrc;
      f16x8 vb = *(const f16x8*)(vsrc + 8);
#pragma unroll
      for (int u = 0; u < 8; ++u) {
        Vt[wid * 16 + u][lane] = va[u];
        Vt[wid * 16 + 8 + u][lane] = vb[u];
      }
    }
    __syncthreads();
    f32x4 s[4] = {};
#pragma unroll
    for (int nt = 0; nt < 4; ++nt)
#pragma unroll
      for (int ks = 0; ks < 2; ++ks) {
        f16x8 kf = *(const f16x8*)&Kt[nt * 16 + lc][ks * 32 + lg * 8];
        s[nt] = mfma16(qf[ks], kf, s[nt]);
      }
    const bool diag = (kt == qi);
#pragma unroll
    for (int nt = 0; nt < 4; ++nt) {
      const int colg = kt * 64 + nt * 16 + lc;
#pragma unroll
      for (int r = 0; r < 4; ++r) {
        float v = s[nt][r] * 0.25f;
        if (diag && colg > qrow_d + r) v = -1e30f;
        s[nt][r] = v;
      }
    }
    float scalev[4];
#pragma unroll
    for (int r = 0; r < 4; ++r) {
      float m = fmaxf(fmaxf(s[0][r], s[1][r]), fmaxf(s[2][r], s[3][r]));
#pragma unroll
      for (int of = 1; of < 16; of <<= 1) m = fmaxf(m, __shfl_xor(m, of));
      const float mn = fmaxf(m_run[r], m);
      scalev[r] = __expf(m_run[r] - mn);
      m_run[r] = mn;
    }
    float ladd[4] = {};
#pragma unroll
    for (int nt = 0; nt < 4; ++nt)
#pragma unroll
      for (int r = 0; r < 4; ++r) {
        const float p = __expf(s[nt][r] - m_run[r]);
        s[nt][r] = p;
        ladd[r] += p;
      }
#pragma unroll
    for (int r = 0; r < 4; ++r) {
      float la = ladd[r];
#pragma unroll
      for (int of = 1; of < 16; of <<= 1) la += __shfl_xor(la, of);
      l_run[r] = l_run[r] * scalev[r] + la;
      o[0][r] *= scalev[r];
      o[1][r] *= scalev[r];
      o[2][r] *= scalev[r];
      o[3][r] *= scalev[r];
    }
#pragma unroll
    for (int nt = 0; nt < 4; ++nt)
#pragma unroll
      for (int r = 0; r < 4; ++r)
        Ps[wid][lg * 4 + r][nt * 16 + lc] = (f16)s[nt][r];
    f16x8 pf[2];
#pragma unroll
    for (int ks = 0; ks < 2; ++ks)
      pf[ks] = *(const f16x8*)&Ps[wid][lc][ks * 32 + lg * 8];
#pragma unroll
    for (int nt = 0; nt < 4; ++nt)
#pragma unroll
      for (int ks = 0; ks < 2; ++ks) {
        f16x8 vf = *(const f16x8*)&Vt[nt * 16 + lc][ks * 32 + lg * 8];
        o[nt] = mfma16(pf[ks], vf, o[nt]);
      }
    __syncthreads();
  }
#pragma unroll
  for (int nt = 0; nt < 4; ++nt)
#pragma unroll
    for (int r = 0; r < 4; ++r) {
      const float val = o[nt][r] / l_run[r];
      const int qrow = qrow_d + r;
      AO[((size_t)(b * T_ + qrow)) * E_ + h * HD_ + nt * 16 + lc] = (f16)val;
    }
}

// ---------------- out GEMM: C = A @ WO^T + bias -----------------------------
__global__ __launch_bounds__(256) void k_gemm_out(
    const f16* __restrict__ A, const f16* __restrict__ W,
    const float* __restrict__ bias, float* __restrict__ C) {
  __shared__ __align__(16) f16 As[128][72];
  __shared__ __align__(16) f16 Bs[128][72];
  const int m0 = blockIdx.x * 128, n0 = blockIdx.y * 128;
  const int tid = threadIdx.x;
  const int wid = tid >> 6, lane = tid & 63;
  const int wr = wid >> 1, wc = wid & 1;
  const int lg = lane >> 4, lc = lane & 15;
  f32x4 acc[4][4] = {};
  for (int kt = 0; kt < E_; kt += 64) {
#pragma unroll
    for (int it = 0; it < 4; ++it) {
      const int r = it * 32 + (tid >> 3);
      const int cs = (tid & 7) * 8;
      *(f16x8*)&As[r][cs] = *(const f16x8*)(A + (size_t)(m0 + r) * E_ + kt + cs);
      *(f16x8*)&Bs[r][cs] = *(const f16x8*)(W + (size_t)(n0 + r) * E_ + kt + cs);
    }
    __syncthreads();
    f16x8 af[4][2], bf[4][2];
#pragma unroll
    for (int mi = 0; mi < 4; ++mi)
#pragma unroll
      for (int ks = 0; ks < 2; ++ks) {
        af[mi][ks] = *(const f16x8*)&As[wr * 64 + mi * 16 + lc][ks * 32 + lg * 8];
        bf[mi][ks] = *(const f16x8*)&Bs[wc * 64 + mi * 16 + lc][ks * 32 + lg * 8];
      }
#pragma unroll
    for (int mi = 0; mi < 4; ++mi)
#pragma unroll
      for (int ni = 0; ni < 4; ++ni)
#pragma unroll
        for (int ks = 0; ks < 2; ++ks)
          acc[mi][ni] = mfma16(af[mi][ks], bf[ni][ks], acc[mi][ni]);
    __syncthreads();
  }
#pragma unroll
  for (int mi = 0; mi < 4; ++mi) {
    const int r0 = m0 + wr * 64 + mi * 16 + lg * 4;
#pragma unroll
    for (int ni = 0; ni < 4; ++ni) {
      const int col = n0 + wc * 64 + ni * 16 + lc;
      const float bv = bias[col];
#pragma unroll
      for (int q = 0; q < 4; ++q)
        C[(size_t)(r0 + q) * E_ + col] = acc[mi][ni][q] + bv;
    }
  }
}

}  // namespace

extern "C" void kernel_launch(void* const* d_in, const int* in_sizes, int n_in,
                              void* d_out, int out_size, void* d_ws, size_t ws_size,
                              hipStream_t stream) {
  (void)in_sizes; (void)n_in; (void)out_size; (void)ws_size;
  const float* x      = (const float*)d_in[0];
  const int*   tok    = (const int*)d_in[1];
  const float* q_wih  = (const float*)d_in[2];
  const float* q_whh  = (const float*)d_in[3];
  const float* q_lin  = (const float*)d_in[4];
  const float* k_wih  = (const float*)d_in[5];
  const float* k_whh  = (const float*)d_in[6];
  const float* k_lin  = (const float*)d_in[7];
  const float* v_emb  = (const float*)d_in[8];
  const float* q_ln_w = (const float*)d_in[9];
  const float* q_ln_b = (const float*)d_in[10];
  const float* k_ln_w = (const float*)d_in[11];
  const float* k_ln_b = (const float*)d_in[12];
  const float* out_w  = (const float*)d_in[13];
  const float* out_b  = (const float*)d_in[14];
  float* outp = (float*)d_out;

  char* ws = (char*)d_ws;
  size_t off = 0;
  auto take = [&](size_t bytes) -> void* {
    void* p = ws + off;
    off += (bytes + 255) & ~(size_t)255;
    return p;
  };
  f16* WQ   = (f16*)take((size_t)E_ * E_ * 2);
  f16* WK   = (f16*)take((size_t)E_ * E_ * 2);
  f16* WO   = (f16*)take((size_t)E_ * E_ * 2);
  f16* WIHQ = (f16*)take((size_t)G3_ * 64 * 2);
  f16* WIHK = (f16*)take((size_t)G3_ * 64 * 2);
  f16* AQ   = (f16*)take((size_t)M_ * E_ * 2);
  f16* AK   = (f16*)take((size_t)M_ * E_ * 2);
  f16* VH   = (f16*)take((size_t)M_ * E_ * 2);
  f16* QH   = (f16*)take((size_t)M_ * E_ * 2);
  f16* KH   = (f16*)take((size_t)M_ * E_ * 2);
  f16* AO   = (f16*)take((size_t)M_ * E_ * 2);
  float* XWQ  = (float*)take((size_t)M_ * G3_ * 4);
  float* XWK  = (float*)take((size_t)M_ * G3_ * 4);
  float* QPRE = (float*)take((size_t)M_ * E_ * 4);
  float* KPRE = (float*)take((size_t)M_ * E_ * 4);

  k_cvt<<<dim3((E_ * E_) / 1024), dim3(256), 0, stream>>>(q_lin, WQ, E_ * E_);
  k_cvt<<<dim3((E_ * E_) / 1024), dim3(256), 0, stream>>>(k_lin, WK, E_ * E_);
  k_cvt<<<dim3((G3_ * 64) / 1024), dim3(256), 0, stream>>>(q_wih, WIHQ, G3_ * 64);
  k_cvt<<<dim3((G3_ * 64) / 1024), dim3(256), 0, stream>>>(k_wih, WIHK, G3_ * 64);

  k_prep<<<dim3(M_), dim3(256), 0, stream>>>(x, tok, WIHQ, WIHK, v_emb, VH, AQ, AK, XWQ, XWK);

  k_mega<<<dim3(521), dim3(256), 0, stream>>>(XWQ, XWK, q_whh, k_whh, AQ, AK,
                                              WQ, WK, QPRE, KPRE, out_w, WO);

  k_fix<<<dim3(M_ / 128, E_ / 128, 2), dim3(256), 0, stream>>>(AQ, AK, WQ, WK, x, QPRE, KPRE);
  k_ln<<<dim3(M_, 2), dim3(256), 0, stream>>>(QPRE, KPRE, q_ln_w, q_ln_b, k_ln_w, k_ln_b, QH, KH);

  k_attn<<<dim3(T_ / 64, B_ * H_), dim3(256), 0, stream>>>(QH, KH, VH, AO);
  k_gemm_out<<<dim3(M_ / 128, E_ / 128), dim3(256), 0, stream>>>(AO, WO, out_b, outp);
}

// Round 4
// 883.775 us; speedup vs baseline: 1.6997x; 1.0000x over previous
//
#include <hip/hip_runtime.h>

// R3: (1) GRU: permlane32_swap pair-pack (no LDS shuffle), exp2-folded gates
//     (scales baked into whh at preload and xw in k_prep), r->n->z dot order.
// (2) Megakernel: GRU block 0 + Q/K partial GEMMs (K=64..1023) + WO cvt run
//     concurrently; k_fix adds the rank-64 GRU term + residual afterwards.

namespace {

constexpr int B_ = 2, T_ = 2048, E_ = 1024, H_ = 16, HD_ = 64, G3_ = 192, M_ = B_ * T_;
constexpr float SRg = -1.4426950408889634f;  // -log2(e), r/z gates
constexpr float SNg = 2.8853900817779268f;   // 2*log2(e), n gate

typedef _Float16 f16;
typedef _Float16 f16x8 __attribute__((ext_vector_type(8)));
typedef _Float16 f16x4 __attribute__((ext_vector_type(4)));
typedef _Float16 f16x2 __attribute__((ext_vector_type(2)));
typedef float f32x4 __attribute__((ext_vector_type(4)));

__device__ __forceinline__ f32x4 mfma16(f16x8 a, f16x8 b, f32x4 c) {
  return __builtin_amdgcn_mfma_f32_16x16x32_f16(a, b, c, 0, 0, 0);
}

#if __has_builtin(__builtin_amdgcn_fdot2)
__device__ __forceinline__ float fdot2(f16x2 a, f16x2 b, float c) {
  return __builtin_amdgcn_fdot2(a, b, c, false);
}
#else
__device__ __forceinline__ float fdot2(f16x2 a, f16x2 b, float c) {
  return c + (float)a[0] * (float)b[0] + (float)a[1] * (float)b[1];
}
#endif

__device__ __forceinline__ float exp2_(float x) {
#if __has_builtin(__builtin_amdgcn_exp2f)
  return __builtin_amdgcn_exp2f(x);
#else
  return exp2f(x);
#endif
}
__device__ __forceinline__ float rcp_(float x) {
#if __has_builtin(__builtin_amdgcn_rcpf)
  return __builtin_amdgcn_rcpf(x);
#else
  return 1.f / x;
#endif
}

// ---------------- fp32 -> fp16 convert ----------------
__global__ __launch_bounds__(256) void k_cvt(const float* __restrict__ s,
                                             f16* __restrict__ d, int n) {
  int i = (blockIdx.x * 256 + threadIdx.x) * 4;
  if (i < n) {
    float4 v = *(const float4*)(s + i);
    f16x4 o = {(f16)v.x, (f16)v.y, (f16)v.z, (f16)v.w};
    *(f16x4*)(d + i) = o;
  }
}

// ---------------- prep: v = silu(x)*emb, x_proj pooling, xw = pool16(x)@wih^T
// xw written PRE-SCALED for exp2-based gates.
__global__ __launch_bounds__(256) void k_prep(
    const float* __restrict__ x, const int* __restrict__ tok,
    const f16* __restrict__ wihq, const f16* __restrict__ wihk,
    const float* __restrict__ v_emb,
    f16* __restrict__ vh, f16* __restrict__ aq, f16* __restrict__ ak,
    float* __restrict__ xwq, float* __restrict__ xwk) {
  __shared__ float xs[E_];
  __shared__ float xp[64];
  const int row = blockIdx.x;
  const int b = row >> 11, t = row & (T_ - 1);
  const int tid = threadIdx.x;
  const float* xrow = x + (size_t)row * E_;
  {
    const int tk = tok[row];
    float4 xv = ((const float4*)xrow)[tid];
    ((float4*)xs)[tid] = xv;
    float4 ev = ((const float4*)(v_emb + (size_t)tk * E_))[tid];
    f16x4 o;
    o[0] = (f16)(xv.x / (1.f + __expf(-xv.x)) * ev.x);
    o[1] = (f16)(xv.y / (1.f + __expf(-xv.y)) * ev.y);
    o[2] = (f16)(xv.z / (1.f + __expf(-xv.z)) * ev.z);
    o[3] = (f16)(xv.w / (1.f + __expf(-xv.w)) * ev.w);
    const int e0 = tid * 4;
    const size_t voff = ((size_t)(b * H_ + (e0 >> 6)) * T_ + t) * HD_ + (e0 & 63);
    *(f16x4*)(vh + voff) = o;
  }
  __syncthreads();
  if (tid < 64) {
    float s = 0.f;
#pragma unroll
    for (int j = 0; j < 16; ++j) s += xs[tid * 16 + j];
    xp[tid] = s * (1.f / 16.f);
  }
  for (int i = tid; i < 960; i += 256) {
    int s0 = (i * 1024) / 960;
    int e0 = ((i + 1) * 1024 + 959) / 960;
    float m = xs[s0];
    if (e0 - s0 == 2) m = (m + xs[s0 + 1]) * 0.5f;
    f16 hv = (f16)m;
    aq[(size_t)row * E_ + 64 + i] = hv;
    ak[(size_t)row * E_ + 64 + i] = hv;
  }
  __syncthreads();
  for (int o = tid; o < 2 * G3_; o += 256) {
    const int chain = o / G3_, g = o % G3_;
    const f16* wrow = (chain ? wihk : wihq) + g * 64;
    float acc = 0.f;
#pragma unroll
    for (int c = 0; c < 8; ++c) {
      f16x8 wv = *(const f16x8*)(wrow + c * 8);
#pragma unroll
      for (int u = 0; u < 8; ++u) acc += xp[c * 8 + u] * (float)wv[u];
    }
    const float sc = (g < 128) ? SRg : SNg;
    (chain ? xwk : xwq)[(size_t)row * G3_ + g] = acc * sc;
  }
}

// ---------------- GRU core: one wave, lane j owns h_j -----------------------
// pairs over K are (k, k+32); h-pair formed via v_permlane32_swap_b32 (VALU).
__device__ __forceinline__ void gru_core(const float* __restrict__ xw,
                                         const float* __restrict__ whh,
                                         f16* __restrict__ a, int lane) {
  f16x2 wr[32], wz[32], wn[32];
#pragma unroll
  for (int i = 0; i < 32; ++i) {
    wr[i] = {(f16)(whh[(size_t)lane * 64 + i] * SRg),
             (f16)(whh[(size_t)lane * 64 + i + 32] * SRg)};
    wz[i] = {(f16)(whh[(size_t)(64 + lane) * 64 + i] * SRg),
             (f16)(whh[(size_t)(64 + lane) * 64 + i + 32] * SRg)};
    wn[i] = {(f16)(whh[(size_t)(128 + lane) * 64 + i] * SNg),
             (f16)(whh[(size_t)(128 + lane) * 64 + i + 32] * SNg)};
  }
  float h = 0.f;
  float xr = xw[lane], xz = xw[64 + lane], xn = xw[128 + lane];
  for (int t = 0; t < T_; ++t) {
    // pack pair (h_l, h_{l+32}) into lanes l<32 via permlane32_swap
    const unsigned hu = (unsigned)__builtin_bit_cast(unsigned short, (f16)h);
    int va = (int)hu, vb = (int)hu;
    asm volatile("v_permlane32_swap_b32 %0, %1" : "+v"(va), "+v"(vb));
    const int pk = (int)(hu | ((unsigned)va << 16));
    int hp[32];
#pragma unroll
    for (int i = 0; i < 32; ++i) hp[i] = __builtin_amdgcn_readlane(pk, i);
    // prefetch next step's (pre-scaled) xw
    const int tn = (t + 1 < T_) ? t + 1 : t;
    const float* nx = xw + (size_t)tn * G3_;
    const float nxr = nx[lane], nxz = nx[64 + lane], nxn = nx[128 + lane];
    // r gate first (its exp hides under n dots)
    float ar = xr;
#pragma unroll
    for (int i = 0; i < 32; ++i)
      ar = fdot2(wr[i], __builtin_bit_cast(f16x2, hp[i]), ar);
    const float r = rcp_(1.f + exp2_(ar));
    float an = 0.f;
#pragma unroll
    for (int i = 0; i < 32; ++i)
      an = fdot2(wn[i], __builtin_bit_cast(f16x2, hp[i]), an);
    const float p2 = fmaf(r, an, xn);              // = 2*log2e*(xn + r*hwn)
    const float n = fmaf(-2.f, rcp_(1.f + exp2_(p2)), 1.f);  // tanh
    float az = xz;
#pragma unroll
    for (int i = 0; i < 32; ++i)
      az = fdot2(wz[i], __builtin_bit_cast(f16x2, hp[i]), az);
    const float z = rcp_(1.f + exp2_(az));
    h = fmaf(z, h - n, n);
    a[(size_t)t * E_ + lane] = (f16)h;
    xr = nxr; xz = nxz; xn = nxn;
  }
}

// ---------------- megakernel: GRU (block 0) + QK partial GEMMs + WO cvt -----
__global__ __launch_bounds__(256, 1) void k_mega(
    const float* __restrict__ xwq, const float* __restrict__ xwk,
    const float* __restrict__ whhq, const float* __restrict__ whhk,
    f16* __restrict__ aq, f16* __restrict__ ak,
    const f16* __restrict__ WQ, const f16* __restrict__ WK,
    float* __restrict__ QPRE, float* __restrict__ KPRE,
    const float* __restrict__ out_w, f16* __restrict__ WO) {
  __shared__ __align__(16) f16 As[128][72];
  __shared__ __align__(16) f16 Bs[128][72];
  const int bx = blockIdx.x;
  const int tid = threadIdx.x;
  if (bx == 0) {
    const int wid = tid >> 6, lane = tid & 63;
    const int qk = wid >> 1, b = wid & 1;
    const float* xw = (qk ? xwk : xwq) + (size_t)b * T_ * G3_;
    const float* whh = qk ? whhk : whhq;
    f16* a = (qk ? ak : aq) + (size_t)b * T_ * E_;
    gru_core(xw, whh, a, lane);
    return;
  }
  if (bx <= 512) {
    // partial GEMM: C = A[:,64:1024] @ W[:,64:1024]^T
    const int bid = bx - 1;
    const int chain = bid >> 8, tile = bid & 255;
    const int m0 = (tile >> 3) * 128, n0 = (tile & 7) * 128;
    const f16* A = chain ? ak : aq;
    const f16* W = chain ? WK : WQ;
    float* C = chain ? KPRE : QPRE;
    const int wid = tid >> 6, lane = tid & 63;
    const int wr = wid >> 1, wc = wid & 1;
    const int lg = lane >> 4, lc = lane & 15;
    f32x4 acc[4][4] = {};
    for (int kt = 64; kt < E_; kt += 64) {
#pragma unroll
      for (int it = 0; it < 4; ++it) {
        const int r = it * 32 + (tid >> 3);
        const int cs = (tid & 7) * 8;
        *(f16x8*)&As[r][cs] = *(const f16x8*)(A + (size_t)(m0 + r) * E_ + kt + cs);
        *(f16x8*)&Bs[r][cs] = *(const f16x8*)(W + (size_t)(n0 + r) * E_ + kt + cs);
      }
      __syncthreads();
      f16x8 af[4][2], bf[4][2];
#pragma unroll
      for (int mi = 0; mi < 4; ++mi)
#pragma unroll
        for (int ks = 0; ks < 2; ++ks) {
          af[mi][ks] = *(const f16x8*)&As[wr * 64 + mi * 16 + lc][ks * 32 + lg * 8];
          bf[mi][ks] = *(const f16x8*)&Bs[wc * 64 + mi * 16 + lc][ks * 32 + lg * 8];
        }
#pragma unroll
      for (int mi = 0; mi < 4; ++mi)
#pragma unroll
        for (int ni = 0; ni < 4; ++ni)
#pragma unroll
          for (int ks = 0; ks < 2; ++ks)
            acc[mi][ni] = mfma16(af[mi][ks], bf[ni][ks], acc[mi][ni]);
      __syncthreads();
    }
#pragma unroll
    for (int mi = 0; mi < 4; ++mi) {
      const int r0 = m0 + wr * 64 + mi * 16 + lg * 4;
#pragma unroll
      for (int ni = 0; ni < 4; ++ni) {
        const int col = n0 + wc * 64 + ni * 16 + lc;
#pragma unroll
        for (int q = 0; q < 4; ++q)
          C[(size_t)(r0 + q) * E_ + col] = acc[mi][ni][q];
      }
    }
    return;
  }
  // WO convert (8 blocks, grid-stride)
  {
    const int cb = bx - 513;
    for (int i = cb * 256 + tid; i < E_ * E_ / 4; i += 8 * 256) {
      float4 v = ((const float4*)out_w)[i];
      f16x4 o = {(f16)v.x, (f16)v.y, (f16)v.z, (f16)v.w};
      *(f16x4*)(WO + (size_t)i * 4) = o;
    }
  }
}

// ---------------- fix: C += A[:,0:64] @ W[:,0:64]^T + x (residual) ----------
__global__ __launch_bounds__(256) void k_fix(
    const f16* __restrict__ aq, const f16* __restrict__ ak,
    const f16* __restrict__ WQ, const f16* __restrict__ WK,
    const float* __restrict__ x, float* __restrict__ QPRE,
    float* __restrict__ KPRE) {
  __shared__ __align__(16) f16 As[128][72];
  __shared__ __align__(16) f16 Bs[128][72];
  const int chain = blockIdx.z;
  const f16* A = chain ? ak : aq;
  const f16* W = chain ? WK : WQ;
  float* C = chain ? KPRE : QPRE;
  const int m0 = blockIdx.x * 128, n0 = blockIdx.y * 128;
  const int tid = threadIdx.x;
  const int wid = tid >> 6, lane = tid & 63;
  const int wr = wid >> 1, wc = wid & 1;
  const int lg = lane >> 4, lc = lane & 15;
#pragma unroll
  for (int it = 0; it < 4; ++it) {
    const int r = it * 32 + (tid >> 3);
    const int cs = (tid & 7) * 8;
    *(f16x8*)&As[r][cs] = *(const f16x8*)(A + (size_t)(m0 + r) * E_ + cs);
    *(f16x8*)&Bs[r][cs] = *(const f16x8*)(W + (size_t)(n0 + r) * E_ + cs);
  }
  __syncthreads();
  f32x4 acc[4][4] = {};
  f16x8 af[4][2], bf[4][2];
#pragma unroll
  for (int mi = 0; mi < 4; ++mi)
#pragma unroll
    for (int ks = 0; ks < 2; ++ks) {
      af[mi][ks] = *(const f16x8*)&As[wr * 64 + mi * 16 + lc][ks * 32 + lg * 8];
      bf[mi][ks] = *(const f16x8*)&Bs[wc * 64 + mi * 16 + lc][ks * 32 + lg * 8];
    }
#pragma unroll
  for (int mi = 0; mi < 4; ++mi)
#pragma unroll
    for (int ni = 0; ni < 4; ++ni)
#pragma unroll
      for (int ks = 0; ks < 2; ++ks)
        acc[mi][ni] = mfma16(af[mi][ks], bf[ni][ks], acc[mi][ni]);
#pragma unroll
  for (int mi = 0; mi < 4; ++mi) {
    const int r0 = m0 + wr * 64 + mi * 16 + lg * 4;
#pragma unroll
    for (int ni = 0; ni < 4; ++ni) {
      const int col = n0 + wc * 64 + ni * 16 + lc;
#pragma unroll
      for (int q = 0; q < 4; ++q) {
        const size_t idx = (size_t)(r0 + q) * E_ + col;
        C[idx] += acc[mi][ni][q] + x[idx];
      }
    }
  }
}

// ---------------- LayerNorm (both chains), write f16 in [B,H,T,HD] ---------
__global__ __launch_bounds__(256) void k_ln(
    const float* __restrict__ qpre, const float* __restrict__ kpre,
    const float* __restrict__ qw, const float* __restrict__ qb,
    const float* __restrict__ kw, const float* __restrict__ kb,
    f16* __restrict__ qh, f16* __restrict__ kh) {
  const int chain = blockIdx.y;
  const float* pre = chain ? kpre : qpre;
  const float* gw = chain ? kw : qw;
  const float* gb = chain ? kb : qb;
  f16* outp = chain ? kh : qh;
  const int row = blockIdx.x;
  const int tid = threadIdx.x;
  const float4 v = ((const float4*)(pre + (size_t)row * E_))[tid];
  float s = v.x + v.y + v.z + v.w;
  float s2 = v.x * v.x + v.y * v.y + v.z * v.z + v.w * v.w;
#pragma unroll
  for (int off = 32; off; off >>= 1) {
    s += __shfl_xor(s, off);
    s2 += __shfl_xor(s2, off);
  }
  __shared__ float red[8];
  const int wid = tid >> 6, lane = tid & 63;
  if (!lane) { red[wid] = s; red[4 + wid] = s2; }
  __syncthreads();
  s = red[0] + red[1] + red[2] + red[3];
  s2 = red[4] + red[5] + red[6] + red[7];
  const float mu = s * (1.f / E_);
  const float inv = rsqrtf(s2 * (1.f / E_) - mu * mu + 1e-5f);
  const float4 w4 = ((const float4*)gw)[tid];
  const float4 b4 = ((const float4*)gb)[tid];
  const int e0 = tid * 4;
  f16x4 o;
  o[0] = (f16)((v.x - mu) * inv * w4.x + b4.x);
  o[1] = (f16)((v.y - mu) * inv * w4.y + b4.y);
  o[2] = (f16)((v.z - mu) * inv * w4.z + b4.z);
  o[3] = (f16)((v.w - mu) * inv * w4.w + b4.w);
  const int b = row >> 11, t = row & (T_ - 1);
  const size_t off2 = ((size_t)(b * H_ + (e0 >> 6)) * T_ + t) * HD_ + (e0 & 63);
  *(f16x4*)(outp + off2) = o;
}

// ---------------- flash attention: causal, scores*2/sqrt(64) = *0.25 -------
__global__ __launch_bounds__(256) void k_attn(const f16* __restrict__ Q,
                                              const f16* __restrict__ K,
                                              const f16* __restrict__ V,
                                              f16* __restrict__ AO) {
  __shared__ __align__(16) f16 Kt[64][72];
  __shared__ __align__(16) f16 Vt[64][72];
  __shared__ __align__(16) f16 Ps[4][16][72];
  const int qi = blockIdx.x, bh = blockIdx.y;
  const int b = bh >> 4, h = bh & 15;
  const int tid = threadIdx.x, wid = tid >> 6, lane = tid & 63;
  const int lg = lane >> 4, lc = lane & 15;
  const size_t hbase = (size_t)bh * T_ * HD_;
  const int qb = qi * 64;
  f16x8 qf[2];
  {
    const int qrow = qb + wid * 16 + lc;
#pragma unroll
    for (int ks = 0; ks < 2; ++ks)
      qf[ks] = *(const f16x8*)(Q + hbase + (size_t)qrow * HD_ + ks * 32 + lg * 8);
  }
  f32x4 o[4] = {};
  float m_run[4] = {-1e30f, -1e30f, -1e30f, -1e30f};
  float l_run[4] = {};
  const int qrow_d = qb + wid * 16 + lg * 4;
  for (int kt = 0; kt <= qi; ++kt) {
    {
      const int r = tid >> 2, cs = (tid & 3) * 16;
      const f16* ksrc = K + hbase + (size_t)(kt * 64 + r) * HD_ + cs;
      *(f16x8*)&Kt[r][cs] = *(const f16x8*)ksrc;
      *(f16x8*)&Kt[r][cs + 8] = *(const f16x8*)(ksrc + 8);
      const f16* vsrc = V + hbase + (size_t)(kt * 64 + lane) * HD_ + wid * 16;
      f16x8 va = *(const f16x8*)vsrc;
      f16x8 vb = *(const f16x8*)(vsrc + 8);
#pragma unroll
      for (int u = 0; u < 8; ++u) {
        Vt[wid * 16 + u][lane] = va[u];
        Vt[wid * 16 + 8 + u][lane] = vb[u];
      }
    }
    __syncthreads();
    f32x4 s[4] = {};
#pragma unroll
    for (int nt = 0; nt < 4; ++nt)
#pragma unroll
      for (int ks = 0; ks < 2; ++ks) {
        f16x8 kf = *(const f16x8*)&Kt[nt * 16 + lc][ks * 32 + lg * 8];
        s[nt] = mfma16(qf[ks], kf, s[nt]);
      }
    const bool diag = (kt == qi);
#pragma unroll
    for (int nt = 0; nt < 4; ++nt) {
      const int colg = kt * 64 + nt * 16 + lc;
#pragma unroll
      for (int r = 0; r < 4; ++r) {
        float v = s[nt][r] * 0.25f;
        if (diag && colg > qrow_d + r) v = -1e30f;
        s[nt][r] = v;
      }
    }
    float scalev[4];
#pragma unroll
    for (int r = 0; r < 4; ++r) {
      float m = fmaxf(fmaxf(s[0][r], s[1][r]), fmaxf(s[2][r], s[3][r]));
#pragma unroll
      for (int of = 1; of < 16; of <<= 1) m = fmaxf(m, __shfl_xor(m, of));
      const float mn = fmaxf(m_run[r], m);
      scalev[r] = __expf(m_run[r] - mn);
      m_run[r] = mn;
    }
    float ladd[4] = {};
#pragma unroll
    for (int nt = 0; nt < 4; ++nt)
#pragma unroll
      for (int r = 0; r < 4; ++r) {
        const float p = __expf(s[nt][r] - m_run[r]);
        s[nt][r] = p;
        ladd[r] += p;
      }
#pragma unroll
    for (int r = 0; r < 4; ++r) {
      float la = ladd[r];
#pragma unroll
      for (int of = 1; of < 16; of <<= 1) la += __shfl_xor(la, of);
      l_run[r] = l_run[r] * scalev[r] + la;
      o[0][r] *= scalev[r];
      o[1][r] *= scalev[r];
      o[2][r] *= scalev[r];
      o[3][r] *= scalev[r];
    }
#pragma unroll
    for (int nt = 0; nt < 4; ++nt)
#pragma unroll
      for (int r = 0; r < 4; ++r)
        Ps[wid][lg * 4 + r][nt * 16 + lc] = (f16)s[nt][r];
    f16x8 pf[2];
#pragma unroll
    for (int ks = 0; ks < 2; ++ks)
      pf[ks] = *(const f16x8*)&Ps[wid][lc][ks * 32 + lg * 8];
#pragma unroll
    for (int nt = 0; nt < 4; ++nt)
#pragma unroll
      for (int ks = 0; ks < 2; ++ks) {
        f16x8 vf = *(const f16x8*)&Vt[nt * 16 + lc][ks * 32 + lg * 8];
        o[nt] = mfma16(pf[ks], vf, o[nt]);
      }
    __syncthreads();
  }
#pragma unroll
  for (int nt = 0; nt < 4; ++nt)
#pragma unroll
    for (int r = 0; r < 4; ++r) {
      const float val = o[nt][r] / l_run[r];
      const int qrow = qrow_d + r;
      AO[((size_t)(b * T_ + qrow)) * E_ + h * HD_ + nt * 16 + lc] = (f16)val;
    }
}

// ---------------- out GEMM: C = A @ WO^T + bias -----------------------------
__global__ __launch_bounds__(256) void k_gemm_out(
    const f16* __restrict__ A, const f16* __restrict__ W,
    const float* __restrict__ bias, float* __restrict__ C) {
  __shared__ __align__(16) f16 As[128][72];
  __shared__ __align__(16) f16 Bs[128][72];
  const int m0 = blockIdx.x * 128, n0 = blockIdx.y * 128;
  const int tid = threadIdx.x;
  const int wid = tid >> 6, lane = tid & 63;
  const int wr = wid >> 1, wc = wid & 1;
  const int lg = lane >> 4, lc = lane & 15;
  f32x4 acc[4][4] = {};
  for (int kt = 0; kt < E_; kt += 64) {
#pragma unroll
    for (int it = 0; it < 4; ++it) {
      const int r = it * 32 + (tid >> 3);
      const int cs = (tid & 7) * 8;
      *(f16x8*)&As[r][cs] = *(const f16x8*)(A + (size_t)(m0 + r) * E_ + kt + cs);
      *(f16x8*)&Bs[r][cs] = *(const f16x8*)(W + (size_t)(n0 + r) * E_ + kt + cs);
    }
    __syncthreads();
    f16x8 af[4][2], bf[4][2];
#pragma unroll
    for (int mi = 0; mi < 4; ++mi)
#pragma unroll
      for (int ks = 0; ks < 2; ++ks) {
        af[mi][ks] = *(const f16x8*)&As[wr * 64 + mi * 16 + lc][ks * 32 + lg * 8];
        bf[mi][ks] = *(const f16x8*)&Bs[wc * 64 + mi * 16 + lc][ks * 32 + lg * 8];
      }
#pragma unroll
    for (int mi = 0; mi < 4; ++mi)
#pragma unroll
      for (int ni = 0; ni < 4; ++ni)
#pragma unroll
        for (int ks = 0; ks < 2; ++ks)
          acc[mi][ni] = mfma16(af[mi][ks], bf[ni][ks], acc[mi][ni]);
    __syncthreads();
  }
#pragma unroll
  for (int mi = 0; mi < 4; ++mi) {
    const int r0 = m0 + wr * 64 + mi * 16 + lg * 4;
#pragma unroll
    for (int ni = 0; ni < 4; ++ni) {
      const int col = n0 + wc * 64 + ni * 16 + lc;
      const float bv = bias[col];
#pragma unroll
      for (int q = 0; q < 4; ++q)
        C[(size_t)(r0 + q) * E_ + col] = acc[mi][ni][q] + bv;
    }
  }
}

}  // namespace

extern "C" void kernel_launch(void* const* d_in, const int* in_sizes, int n_in,
                              void* d_out, int out_size, void* d_ws, size_t ws_size,
                              hipStream_t stream) {
  (void)in_sizes; (void)n_in; (void)out_size; (void)ws_size;
  const float* x      = (const float*)d_in[0];
  const int*   tok    = (const int*)d_in[1];
  const float* q_wih  = (const float*)d_in[2];
  const float* q_whh  = (const float*)d_in[3];
  const float* q_lin  = (const float*)d_in[4];
  const float* k_wih  = (const float*)d_in[5];
  const float* k_whh  = (const float*)d_in[6];
  const float* k_lin  = (const float*)d_in[7];
  const float* v_emb  = (const float*)d_in[8];
  const float* q_ln_w = (const float*)d_in[9];
  const float* q_ln_b = (const float*)d_in[10];
  const float* k_ln_w = (const float*)d_in[11];
  const float* k_ln_b = (const float*)d_in[12];
  const float* out_w  = (const float*)d_in[13];
  const float* out_b  = (const float*)d_in[14];
  float* outp = (float*)d_out;

  char* ws = (char*)d_ws;
  size_t off = 0;
  auto take = [&](size_t bytes) -> void* {
    void* p = ws + off;
    off += (bytes + 255) & ~(size_t)255;
    return p;
  };
  f16* WQ   = (f16*)take((size_t)E_ * E_ * 2);
  f16* WK   = (f16*)take((size_t)E_ * E_ * 2);
  f16* WO   = (f16*)take((size_t)E_ * E_ * 2);
  f16* WIHQ = (f16*)take((size_t)G3_ * 64 * 2);
  f16* WIHK = (f16*)take((size_t)G3_ * 64 * 2);
  f16* AQ   = (f16*)take((size_t)M_ * E_ * 2);
  f16* AK   = (f16*)take((size_t)M_ * E_ * 2);
  f16* VH   = (f16*)take((size_t)M_ * E_ * 2);
  f16* QH   = (f16*)take((size_t)M_ * E_ * 2);
  f16* KH   = (f16*)take((size_t)M_ * E_ * 2);
  f16* AO   = (f16*)take((size_t)M_ * E_ * 2);
  float* XWQ  = (float*)take((size_t)M_ * G3_ * 4);
  float* XWK  = (float*)take((size_t)M_ * G3_ * 4);
  float* QPRE = (float*)take((size_t)M_ * E_ * 4);
  float* KPRE = (float*)take((size_t)M_ * E_ * 4);

  k_cvt<<<dim3((E_ * E_) / 1024), dim3(256), 0, stream>>>(q_lin, WQ, E_ * E_);
  k_cvt<<<dim3((E_ * E_) / 1024), dim3(256), 0, stream>>>(k_lin, WK, E_ * E_);
  k_cvt<<<dim3((G3_ * 64) / 1024), dim3(256), 0, stream>>>(q_wih, WIHQ, G3_ * 64);
  k_cvt<<<dim3((G3_ * 64) / 1024), dim3(256), 0, stream>>>(k_wih, WIHK, G3_ * 64);

  k_prep<<<dim3(M_), dim3(256), 0, stream>>>(x, tok, WIHQ, WIHK, v_emb, VH, AQ, AK, XWQ, XWK);

  k_mega<<<dim3(521), dim3(256), 0, stream>>>(XWQ, XWK, q_whh, k_whh, AQ, AK,
                                              WQ, WK, QPRE, KPRE, out_w, WO);

  k_fix<<<dim3(M_ / 128, E_ / 128, 2), dim3(256), 0, stream>>>(AQ, AK, WQ, WK, x, QPRE, KPRE);
  k_ln<<<dim3(M_, 2), dim3(256), 0, stream>>>(QPRE, KPRE, q_ln_w, q_ln_b, k_ln_w, k_ln_b, QH, KH);

  k_attn<<<dim3(T_ / 64, B_ * H_), dim3(256), 0, stream>>>(QH, KH, VH, AO);
  k_gemm_out<<<dim3(M_ / 128, E_ / 128), dim3(256), 0, stream>>>(AO, WO, out_b, outp);
}

// Round 5
// 883.401 us; speedup vs baseline: 1.7004x; 1.0004x over previous
//
#include <hip/hip_runtime.h>

// R3: (1) GRU: permlane32_swap pair-pack (no LDS shuffle), exp2-folded gates
//     (scales baked into whh at preload and xw in k_prep), r->n->z dot order.
// (2) Megakernel: GRU block 0 + Q/K partial GEMMs (K=64..1023) + WO cvt run
//     concurrently; k_fix adds the rank-64 GRU term + residual afterwards.

namespace {

constexpr int B_ = 2, T_ = 2048, E_ = 1024, H_ = 16, HD_ = 64, G3_ = 192, M_ = B_ * T_;
constexpr float SRg = -1.4426950408889634f;  // -log2(e), r/z gates
constexpr float SNg = 2.8853900817779268f;   // 2*log2(e), n gate

typedef _Float16 f16;
typedef _Float16 f16x8 __attribute__((ext_vector_type(8)));
typedef _Float16 f16x4 __attribute__((ext_vector_type(4)));
typedef _Float16 f16x2 __attribute__((ext_vector_type(2)));
typedef float f32x4 __attribute__((ext_vector_type(4)));

__device__ __forceinline__ f32x4 mfma16(f16x8 a, f16x8 b, f32x4 c) {
  return __builtin_amdgcn_mfma_f32_16x16x32_f16(a, b, c, 0, 0, 0);
}

#if __has_builtin(__builtin_amdgcn_fdot2)
__device__ __forceinline__ float fdot2(f16x2 a, f16x2 b, float c) {
  return __builtin_amdgcn_fdot2(a, b, c, false);
}
#else
__device__ __forceinline__ float fdot2(f16x2 a, f16x2 b, float c) {
  return c + (float)a[0] * (float)b[0] + (float)a[1] * (float)b[1];
}
#endif

__device__ __forceinline__ float exp2_(float x) {
#if __has_builtin(__builtin_amdgcn_exp2f)
  return __builtin_amdgcn_exp2f(x);
#else
  return exp2f(x);
#endif
}
__device__ __forceinline__ float rcp_(float x) {
#if __has_builtin(__builtin_amdgcn_rcpf)
  return __builtin_amdgcn_rcpf(x);
#else
  return 1.f / x;
#endif
}

// ---------------- fp32 -> fp16 convert ----------------
__global__ __launch_bounds__(256) void k_cvt(const float* __restrict__ s,
                                             f16* __restrict__ d, int n) {
  int i = (blockIdx.x * 256 + threadIdx.x) * 4;
  if (i < n) {
    float4 v = *(const float4*)(s + i);
    f16x4 o = {(f16)v.x, (f16)v.y, (f16)v.z, (f16)v.w};
    *(f16x4*)(d + i) = o;
  }
}

// ---------------- prep: v = silu(x)*emb, x_proj pooling, xw = pool16(x)@wih^T
// xw written PRE-SCALED for exp2-based gates.
__global__ __launch_bounds__(256) void k_prep(
    const float* __restrict__ x, const int* __restrict__ tok,
    const f16* __restrict__ wihq, const f16* __restrict__ wihk,
    const float* __restrict__ v_emb,
    f16* __restrict__ vh, f16* __restrict__ aq, f16* __restrict__ ak,
    float* __restrict__ xwq, float* __restrict__ xwk) {
  __shared__ float xs[E_];
  __shared__ float xp[64];
  const int row = blockIdx.x;
  const int b = row >> 11, t = row & (T_ - 1);
  const int tid = threadIdx.x;
  const float* xrow = x + (size_t)row * E_;
  {
    const int tk = tok[row];
    float4 xv = ((const float4*)xrow)[tid];
    ((float4*)xs)[tid] = xv;
    float4 ev = ((const float4*)(v_emb + (size_t)tk * E_))[tid];
    f16x4 o;
    o[0] = (f16)(xv.x / (1.f + __expf(-xv.x)) * ev.x);
    o[1] = (f16)(xv.y / (1.f + __expf(-xv.y)) * ev.y);
    o[2] = (f16)(xv.z / (1.f + __expf(-xv.z)) * ev.z);
    o[3] = (f16)(xv.w / (1.f + __expf(-xv.w)) * ev.w);
    const int e0 = tid * 4;
    const size_t voff = ((size_t)(b * H_ + (e0 >> 6)) * T_ + t) * HD_ + (e0 & 63);
    *(f16x4*)(vh + voff) = o;
  }
  __syncthreads();
  if (tid < 64) {
    float s = 0.f;
#pragma unroll
    for (int j = 0; j < 16; ++j) s += xs[tid * 16 + j];
    xp[tid] = s * (1.f / 16.f);
  }
  for (int i = tid; i < 960; i += 256) {
    int s0 = (i * 1024) / 960;
    int e0 = ((i + 1) * 1024 + 959) / 960;
    float m = xs[s0];
    if (e0 - s0 == 2) m = (m + xs[s0 + 1]) * 0.5f;
    f16 hv = (f16)m;
    aq[(size_t)row * E_ + 64 + i] = hv;
    ak[(size_t)row * E_ + 64 + i] = hv;
  }
  __syncthreads();
  for (int o = tid; o < 2 * G3_; o += 256) {
    const int chain = o / G3_, g = o % G3_;
    const f16* wrow = (chain ? wihk : wihq) + g * 64;
    float acc = 0.f;
#pragma unroll
    for (int c = 0; c < 8; ++c) {
      f16x8 wv = *(const f16x8*)(wrow + c * 8);
#pragma unroll
      for (int u = 0; u < 8; ++u) acc += xp[c * 8 + u] * (float)wv[u];
    }
    const float sc = (g < 128) ? SRg : SNg;
    (chain ? xwk : xwq)[(size_t)row * G3_ + g] = acc * sc;
  }
}

// ---------------- GRU core: one wave, lane j owns h_j -----------------------
// pairs over K are (k, k+32); h-pair formed via v_permlane32_swap_b32 (VALU).
__device__ __forceinline__ void gru_core(const float* __restrict__ xw,
                                         const float* __restrict__ whh,
                                         f16* __restrict__ a, int lane) {
  f16x2 wr[32], wz[32], wn[32];
#pragma unroll
  for (int i = 0; i < 32; ++i) {
    wr[i] = {(f16)(whh[(size_t)lane * 64 + i] * SRg),
             (f16)(whh[(size_t)lane * 64 + i + 32] * SRg)};
    wz[i] = {(f16)(whh[(size_t)(64 + lane) * 64 + i] * SRg),
             (f16)(whh[(size_t)(64 + lane) * 64 + i + 32] * SRg)};
    wn[i] = {(f16)(whh[(size_t)(128 + lane) * 64 + i] * SNg),
             (f16)(whh[(size_t)(128 + lane) * 64 + i + 32] * SNg)};
  }
  float h = 0.f;
  float xr = xw[lane], xz = xw[64 + lane], xn = xw[128 + lane];
  for (int t = 0; t < T_; ++t) {
    // pack pair (h_l, h_{l+32}) into lanes l<32 via permlane32_swap
    const unsigned hu = (unsigned)__builtin_bit_cast(unsigned short, (f16)h);
    int va = (int)hu, vb = (int)hu;
    asm volatile("v_permlane32_swap_b32 %0, %1" : "+v"(va), "+v"(vb));
    const int pk = (int)(hu | ((unsigned)va << 16));
    int hp[32];
#pragma unroll
    for (int i = 0; i < 32; ++i) hp[i] = __builtin_amdgcn_readlane(pk, i);
    // prefetch next step's (pre-scaled) xw
    const int tn = (t + 1 < T_) ? t + 1 : t;
    const float* nx = xw + (size_t)tn * G3_;
    const float nxr = nx[lane], nxz = nx[64 + lane], nxn = nx[128 + lane];
    // r gate first (its exp hides under n dots)
    float ar = xr;
#pragma unroll
    for (int i = 0; i < 32; ++i)
      ar = fdot2(wr[i], __builtin_bit_cast(f16x2, hp[i]), ar);
    const float r = rcp_(1.f + exp2_(ar));
    float an = 0.f;
#pragma unroll
    for (int i = 0; i < 32; ++i)
      an = fdot2(wn[i], __builtin_bit_cast(f16x2, hp[i]), an);
    const float p2 = fmaf(r, an, xn);              // = 2*log2e*(xn + r*hwn)
    const float n = fmaf(-2.f, rcp_(1.f + exp2_(p2)), 1.f);  // tanh
    float az = xz;
#pragma unroll
    for (int i = 0; i < 32; ++i)
      az = fdot2(wz[i], __builtin_bit_cast(f16x2, hp[i]), az);
    const float z = rcp_(1.f + exp2_(az));
    h = fmaf(z, h - n, n);
    a[(size_t)t * E_ + lane] = (f16)h;
    xr = nxr; xz = nxz; xn = nxn;
  }
}

// ---------------- megakernel: GRU (block 0) + QK partial GEMMs + WO cvt -----
__global__ __launch_bounds__(256, 1) void k_mega(
    const float* __restrict__ xwq, const float* __restrict__ xwk,
    const float* __restrict__ whhq, const float* __restrict__ whhk,
    f16* __restrict__ aq, f16* __restrict__ ak,
    const f16* __restrict__ WQ, const f16* __restrict__ WK,
    float* __restrict__ QPRE, float* __restrict__ KPRE,
    const float* __restrict__ out_w, f16* __restrict__ WO) {
  __shared__ __align__(16) f16 As[128][72];
  __shared__ __align__(16) f16 Bs[128][72];
  const int bx = blockIdx.x;
  const int tid = threadIdx.x;
  if (bx == 0) {
    const int wid = tid >> 6, lane = tid & 63;
    const int qk = wid >> 1, b = wid & 1;
    const float* xw = (qk ? xwk : xwq) + (size_t)b * T_ * G3_;
    const float* whh = qk ? whhk : whhq;
    f16* a = (qk ? ak : aq) + (size_t)b * T_ * E_;
    gru_core(xw, whh, a, lane);
    return;
  }
  if (bx <= 512) {
    // partial GEMM: C = A[:,64:1024] @ W[:,64:1024]^T
    const int bid = bx - 1;
    const int chain = bid >> 8, tile = bid & 255;
    const int m0 = (tile >> 3) * 128, n0 = (tile & 7) * 128;
    const f16* A = chain ? ak : aq;
    const f16* W = chain ? WK : WQ;
    float* C = chain ? KPRE : QPRE;
    const int wid = tid >> 6, lane = tid & 63;
    const int wr = wid >> 1, wc = wid & 1;
    const int lg = lane >> 4, lc = lane & 15;
    f32x4 acc[4][4] = {};
    for (int kt = 64; kt < E_; kt += 64) {
#pragma unroll
      for (int it = 0; it < 4; ++it) {
        const int r = it * 32 + (tid >> 3);
        const int cs = (tid & 7) * 8;
        *(f16x8*)&As[r][cs] = *(const f16x8*)(A + (size_t)(m0 + r) * E_ + kt + cs);
        *(f16x8*)&Bs[r][cs] = *(const f16x8*)(W + (size_t)(n0 + r) * E_ + kt + cs);
      }
      __syncthreads();
      f16x8 af[4][2], bf[4][2];
#pragma unroll
      for (int mi = 0; mi < 4; ++mi)
#pragma unroll
        for (int ks = 0; ks < 2; ++ks) {
          af[mi][ks] = *(const f16x8*)&As[wr * 64 + mi * 16 + lc][ks * 32 + lg * 8];
          bf[mi][ks] = *(const f16x8*)&Bs[wc * 64 + mi * 16 + lc][ks * 32 + lg * 8];
        }
#pragma unroll
      for (int mi = 0; mi < 4; ++mi)
#pragma unroll
        for (int ni = 0; ni < 4; ++ni)
#pragma unroll
          for (int ks = 0; ks < 2; ++ks)
            acc[mi][ni] = mfma16(af[mi][ks], bf[ni][ks], acc[mi][ni]);
      __syncthreads();
    }
#pragma unroll
    for (int mi = 0; mi < 4; ++mi) {
      const int r0 = m0 + wr * 64 + mi * 16 + lg * 4;
#pragma unroll
      for (int ni = 0; ni < 4; ++ni) {
        const int col = n0 + wc * 64 + ni * 16 + lc;
#pragma unroll
        for (int q = 0; q < 4; ++q)
          C[(size_t)(r0 + q) * E_ + col] = acc[mi][ni][q];
      }
    }
    return;
  }
  // WO convert (8 blocks, grid-stride)
  {
    const int cb = bx - 513;
    for (int i = cb * 256 + tid; i < E_ * E_ / 4; i += 8 * 256) {
      float4 v = ((const float4*)out_w)[i];
      f16x4 o = {(f16)v.x, (f16)v.y, (f16)v.z, (f16)v.w};
      *(f16x4*)(WO + (size_t)i * 4) = o;
    }
  }
}

// ---------------- fix: C += A[:,0:64] @ W[:,0:64]^T + x (residual) ----------
__global__ __launch_bounds__(256) void k_fix(
    const f16* __restrict__ aq, const f16* __restrict__ ak,
    const f16* __restrict__ WQ, const f16* __restrict__ WK,
    const float* __restrict__ x, float* __restrict__ QPRE,
    float* __restrict__ KPRE) {
  __shared__ __align__(16) f16 As[128][72];
  __shared__ __align__(16) f16 Bs[128][72];
  const int chain = blockIdx.z;
  const f16* A = chain ? ak : aq;
  const f16* W = chain ? WK : WQ;
  float* C = chain ? KPRE : QPRE;
  const int m0 = blockIdx.x * 128, n0 = blockIdx.y * 128;
  const int tid = threadIdx.x;
  const int wid = tid >> 6, lane = tid & 63;
  const int wr = wid >> 1, wc = wid & 1;
  const int lg = lane >> 4, lc = lane & 15;
#pragma unroll
  for (int it = 0; it < 4; ++it) {
    const int r = it * 32 + (tid >> 3);
    const int cs = (tid & 7) * 8;
    *(f16x8*)&As[r][cs] = *(const f16x8*)(A + (size_t)(m0 + r) * E_ + cs);
    *(f16x8*)&Bs[r][cs] = *(const f16x8*)(W + (size_t)(n0 + r) * E_ + cs);
  }
  __syncthreads();
  f32x4 acc[4][4] = {};
  f16x8 af[4][2], bf[4][2];
#pragma unroll
  for (int mi = 0; mi < 4; ++mi)
#pragma unroll
    for (int ks = 0; ks < 2; ++ks) {
      af[mi][ks] = *(const f16x8*)&As[wr * 64 + mi * 16 + lc][ks * 32 + lg * 8];
      bf[mi][ks] = *(const f16x8*)&Bs[wc * 64 + mi * 16 + lc][ks * 32 + lg * 8];
    }
#pragma unroll
  for (int mi = 0; mi < 4; ++mi)
#pragma unroll
    for (int ni = 0; ni < 4; ++ni)
#pragma unroll
      for (int ks = 0; ks < 2; ++ks)
        acc[mi][ni] = mfma16(af[mi][ks], bf[ni][ks], acc[mi][ni]);
#pragma unroll
  for (int mi = 0; mi < 4; ++mi) {
    const int r0 = m0 + wr * 64 + mi * 16 + lg * 4;
#pragma unroll
    for (int ni = 0; ni < 4; ++ni) {
      const int col = n0 + wc * 64 + ni * 16 + lc;
#pragma unroll
      for (int q = 0; q < 4; ++q) {
        const size_t idx = (size_t)(r0 + q) * E_ + col;
        C[idx] += acc[mi][ni][q] + x[idx];
      }
    }
  }
}

// ---------------- LayerNorm (both chains), write f16 in [B,H,T,HD] ---------
__global__ __launch_bounds__(256) void k_ln(
    const float* __restrict__ qpre, const float* __restrict__ kpre,
    const float* __restrict__ qw, const float* __restrict__ qb,
    const float* __restrict__ kw, const float* __restrict__ kb,
    f16* __restrict__ qh, f16* __restrict__ kh) {
  const int chain = blockIdx.y;
  const float* pre = chain ? kpre : qpre;
  const float* gw = chain ? kw : qw;
  const float* gb = chain ? kb : qb;
  f16* outp = chain ? kh : qh;
  const int row = blockIdx.x;
  const int tid = threadIdx.x;
  const float4 v = ((const float4*)(pre + (size_t)row * E_))[tid];
  float s = v.x + v.y + v.z + v.w;
  float s2 = v.x * v.x + v.y * v.y + v.z * v.z + v.w * v.w;
#pragma unroll
  for (int off = 32; off; off >>= 1) {
    s += __shfl_xor(s, off);
    s2 += __shfl_xor(s2, off);
  }
  __shared__ float red[8];
  const int wid = tid >> 6, lane = tid & 63;
  if (!lane) { red[wid] = s; red[4 + wid] = s2; }
  __syncthreads();
  s = red[0] + red[1] + red[2] + red[3];
  s2 = red[4] + red[5] + red[6] + red[7];
  const float mu = s * (1.f / E_);
  const float inv = rsqrtf(s2 * (1.f / E_) - mu * mu + 1e-5f);
  const float4 w4 = ((const float4*)gw)[tid];
  const float4 b4 = ((const float4*)gb)[tid];
  const int e0 = tid * 4;
  f16x4 o;
  o[0] = (f16)((v.x - mu) * inv * w4.x + b4.x);
  o[1] = (f16)((v.y - mu) * inv * w4.y + b4.y);
  o[2] = (f16)((v.z - mu) * inv * w4.z + b4.z);
  o[3] = (f16)((v.w - mu) * inv * w4.w + b4.w);
  const int b = row >> 11, t = row & (T_ - 1);
  const size_t off2 = ((size_t)(b * H_ + (e0 >> 6)) * T_ + t) * HD_ + (e0 & 63);
  *(f16x4*)(outp + off2) = o;
}

// ---------------- flash attention: causal, scores*2/sqrt(64) = *0.25 -------
__global__ __launch_bounds__(256) void k_attn(const f16* __restrict__ Q,
                                              const f16* __restrict__ K,
                                              const f16* __restrict__ V,
                                              f16* __restrict__ AO) {
  __shared__ __align__(16) f16 Kt[64][72];
  __shared__ __align__(16) f16 Vt[64][72];
  __shared__ __align__(16) f16 Ps[4][16][72];
  const int qi = blockIdx.x, bh = blockIdx.y;
  const int b = bh >> 4, h = bh & 15;
  const int tid = threadIdx.x, wid = tid >> 6, lane = tid & 63;
  const int lg = lane >> 4, lc = lane & 15;
  const size_t hbase = (size_t)bh * T_ * HD_;
  const int qb = qi * 64;
  f16x8 qf[2];
  {
    const int qrow = qb + wid * 16 + lc;
#pragma unroll
    for (int ks = 0; ks < 2; ++ks)
      qf[ks] = *(const f16x8*)(Q + hbase + (size_t)qrow * HD_ + ks * 32 + lg * 8);
  }
  f32x4 o[4] = {};
  float m_run[4] = {-1e30f, -1e30f, -1e30f, -1e30f};
  float l_run[4] = {};
  const int qrow_d = qb + wid * 16 + lg * 4;
  for (int kt = 0; kt <= qi; ++kt) {
    {
      const int r = tid >> 2, cs = (tid & 3) * 16;
      const f16* ksrc = K + hbase + (size_t)(kt * 64 + r) * HD_ + cs;
      *(f16x8*)&Kt[r][cs] = *(const f16x8*)ksrc;
      *(f16x8*)&Kt[r][cs + 8] = *(const f16x8*)(ksrc + 8);
      const f16* vsrc = V + hbase + (size_t)(kt * 64 + lane) * HD_ + wid * 16;
      f16x8 va = *(const f16x8*)vsrc;
      f16x8 vb = *(const f16x8*)(vsrc + 8);
#pragma unroll
      for (int u = 0; u < 8; ++u) {
        Vt[wid * 16 + u][lane] = va[u];
        Vt[wid * 16 + 8 + u][lane] = vb[u];
      }
    }
    __syncthreads();
    f32x4 s[4] = {};
#pragma unroll
    for (int nt = 0; nt < 4; ++nt)
#pragma unroll
      for (int ks = 0; ks < 2; ++ks) {
        f16x8 kf = *(const f16x8*)&Kt[nt * 16 + lc][ks * 32 + lg * 8];
        s[nt] = mfma16(qf[ks], kf, s[nt]);
      }
    const bool diag = (kt == qi);
#pragma unroll
    for (int nt = 0; nt < 4; ++nt) {
      const int colg = kt * 64 + nt * 16 + lc;
#pragma unroll
      for (int r = 0; r < 4; ++r) {
        float v = s[nt][r] * 0.25f;
        if (diag && colg > qrow_d + r) v = -1e30f;
        s[nt][r] = v;
      }
    }
    float scalev[4];
#pragma unroll
    for (int r = 0; r < 4; ++r) {
      float m = fmaxf(fmaxf(s[0][r], s[1][r]), fmaxf(s[2][r], s[3][r]));
#pragma unroll
      for (int of = 1; of < 16; of <<= 1) m = fmaxf(m, __shfl_xor(m, of));
      const float mn = fmaxf(m_run[r], m);
      scalev[r] = __expf(m_run[r] - mn);
      m_run[r] = mn;
    }
    float ladd[4] = {};
#pragma unroll
    for (int nt = 0; nt < 4; ++nt)
#pragma unroll
      for (int r = 0; r < 4; ++r) {
        const float p = __expf(s[nt][r] - m_run[r]);
        s[nt][r] = p;
        ladd[r] += p;
      }
#pragma unroll
    for (int r = 0; r < 4; ++r) {
      float la = ladd[r];
#pragma unroll
      for (int of = 1; of < 16; of <<= 1) la += __shfl_xor(la, of);
      l_run[r] = l_run[r] * scalev[r] + la;
      o[0][r] *= scalev[r];
      o[1][r] *= scalev[r];
      o[2][r] *= scalev[r];
      o[3][r] *= scalev[r];
    }
#pragma unroll
    for (int nt = 0; nt < 4; ++nt)
#pragma unroll
      for (int r = 0; r < 4; ++r)
        Ps[wid][lg * 4 + r][nt * 16 + lc] = (f16)s[nt][r];
    f16x8 pf[2];
#pragma unroll
    for (int ks = 0; ks < 2; ++ks)
      pf[ks] = *(const f16x8*)&Ps[wid][lc][ks * 32 + lg * 8];
#pragma unroll
    for (int nt = 0; nt < 4; ++nt)
#pragma unroll
      for (int ks = 0; ks < 2; ++ks) {
        f16x8 vf = *(const f16x8*)&Vt[nt * 16 + lc][ks * 32 + lg * 8];
        o[nt] = mfma16(pf[ks], vf, o[nt]);
      }
    __syncthreads();
  }
#pragma unroll
  for (int nt = 0; nt < 4; ++nt)
#pragma unroll
    for (int r = 0; r < 4; ++r) {
      const float val = o[nt][r] / l_run[r];
      const int qrow = qrow_d + r;
      AO[((size_t)(b * T_ + qrow)) * E_ + h * HD_ + nt * 16 + lc] = (f16)val;
    }
}

// ---------------- out GEMM: C = A @ WO^T + bias -----------------------------
__global__ __launch_bounds__(256) void k_gemm_out(
    const f16* __restrict__ A, const f16* __restrict__ W,
    const float* __restrict__ bias, float* __restrict__ C) {
  __shared__ __align__(16) f16 As[128][72];
  __shared__ __align__(16) f16 Bs[128][72];
  const int m0 = blockIdx.x * 128, n0 = blockIdx.y * 128;
  const int tid = threadIdx.x;
  const int wid = tid >> 6, lane = tid & 63;
  const int wr = wid >> 1, wc = wid & 1;
  const int lg = lane >> 4, lc = lane & 15;
  f32x4 acc[4][4] = {};
  for (int kt = 0; kt < E_; kt += 64) {
#pragma unroll
    for (int it = 0; it < 4; ++it) {
      const int r = it * 32 + (tid >> 3);
      const int cs = (tid & 7) * 8;
      *(f16x8*)&As[r][cs] = *(const f16x8*)(A + (size_t)(m0 + r) * E_ + kt + cs);
      *(f16x8*)&Bs[r][cs] = *(const f16x8*)(W + (size_t)(n0 + r) * E_ + kt + cs);
    }
    __syncthreads();
    f16x8 af[4][2], bf[4][2];
#pragma unroll
    for (int mi = 0; mi < 4; ++mi)
#pragma unroll
      for (int ks = 0; ks < 2; ++ks) {
        af[mi][ks] = *(const f16x8*)&As[wr * 64 + mi * 16 + lc][ks * 32 + lg * 8];
        bf[mi][ks] = *(const f16x8*)&Bs[wc * 64 + mi * 16 + lc][ks * 32 + lg * 8];
      }
#pragma unroll
    for (int mi = 0; mi < 4; ++mi)
#pragma unroll
      for (int ni = 0; ni < 4; ++ni)
#pragma unroll
        for (int ks = 0; ks < 2; ++ks)
          acc[mi][ni] = mfma16(af[mi][ks], bf[ni][ks], acc[mi][ni]);
    __syncthreads();
  }
#pragma unroll
  for (int mi = 0; mi < 4; ++mi) {
    const int r0 = m0 + wr * 64 + mi * 16 + lg * 4;
#pragma unroll
    for (int ni = 0; ni < 4; ++ni) {
      const int col = n0 + wc * 64 + ni * 16 + lc;
      const float bv = bias[col];
#pragma unroll
      for (int q = 0; q < 4; ++q)
        C[(size_t)(r0 + q) * E_ + col] = acc[mi][ni][q] + bv;
    }
  }
}

}  // namespace

extern "C" void kernel_launch(void* const* d_in, const int* in_sizes, int n_in,
                              void* d_out, int out_size, void* d_ws, size_t ws_size,
                              hipStream_t stream) {
  (void)in_sizes; (void)n_in; (void)out_size; (void)ws_size;
  const float* x      = (const float*)d_in[0];
  const int*   tok    = (const int*)d_in[1];
  const float* q_wih  = (const float*)d_in[2];
  const float* q_whh  = (const float*)d_in[3];
  const float* q_lin  = (const float*)d_in[4];
  const float* k_wih  = (const float*)d_in[5];
  const float* k_whh  = (const float*)d_in[6];
  const float* k_lin  = (const float*)d_in[7];
  const float* v_emb  = (const float*)d_in[8];
  const float* q_ln_w = (const float*)d_in[9];
  const float* q_ln_b = (const float*)d_in[10];
  const float* k_ln_w = (const float*)d_in[11];
  const float* k_ln_b = (const float*)d_in[12];
  const float* out_w  = (const float*)d_in[13];
  const float* out_b  = (const float*)d_in[14];
  float* outp = (float*)d_out;

  char* ws = (char*)d_ws;
  size_t off = 0;
  auto take = [&](size_t bytes) -> void* {
    void* p = ws + off;
    off += (bytes + 255) & ~(size_t)255;
    return p;
  };
  f16* WQ   = (f16*)take((size_t)E_ * E_ * 2);
  f16* WK   = (f16*)take((size_t)E_ * E_ * 2);
  f16* WO   = (f16*)take((size_t)E_ * E_ * 2);
  f16* WIHQ = (f16*)take((size_t)G3_ * 64 * 2);
  f16* WIHK = (f16*)take((size_t)G3_ * 64 * 2);
  f16* AQ   = (f16*)take((size_t)M_ * E_ * 2);
  f16* AK   = (f16*)take((size_t)M_ * E_ * 2);
  f16* VH   = (f16*)take((size_t)M_ * E_ * 2);
  f16* QH   = (f16*)take((size_t)M_ * E_ * 2);
  f16* KH   = (f16*)take((size_t)M_ * E_ * 2);
  f16* AO   = (f16*)take((size_t)M_ * E_ * 2);
  float* XWQ  = (float*)take((size_t)M_ * G3_ * 4);
  float* XWK  = (float*)take((size_t)M_ * G3_ * 4);
  float* QPRE = (float*)take((size_t)M_ * E_ * 4);
  float* KPRE = (float*)take((size_t)M_ * E_ * 4);

  k_cvt<<<dim3((E_ * E_) / 1024), dim3(256), 0, stream>>>(q_lin, WQ, E_ * E_);
  k_cvt<<<dim3((E_ * E_) / 1024), dim3(256), 0, stream>>>(k_lin, WK, E_ * E_);
  k_cvt<<<dim3((G3_ * 64) / 1024), dim3(256), 0, stream>>>(q_wih, WIHQ, G3_ * 64);
  k_cvt<<<dim3((G3_ * 64) / 1024), dim3(256), 0, stream>>>(k_wih, WIHK, G3_ * 64);

  k_prep<<<dim3(M_), dim3(256), 0, stream>>>(x, tok, WIHQ, WIHK, v_emb, VH, AQ, AK, XWQ, XWK);

  k_mega<<<dim3(521), dim3(256), 0, stream>>>(XWQ, XWK, q_whh, k_whh, AQ, AK,
                                              WQ, WK, QPRE, KPRE, out_w, WO);

  k_fix<<<dim3(M_ / 128, E_ / 128, 2), dim3(256), 0, stream>>>(AQ, AK, WQ, WK, x, QPRE, KPRE);
  k_ln<<<dim3(M_, 2), dim3(256), 0, stream>>>(QPRE, KPRE, q_ln_w, q_ln_b, k_ln_w, k_ln_b, QH, KH);

  k_attn<<<dim3(T_ / 64, B_ * H_), dim3(256), 0, stream>>>(QH, KH, VH, AO);
  k_gemm_out<<<dim3(M_ / 128, E_ / 128), dim3(256), 0, stream>>>(AO, WO, out_b, outp);
}

// Round 6
// 882.865 us; speedup vs baseline: 1.7014x; 1.0006x over previous
//
#include <hip/hip_runtime.h>

// R3: (1) GRU: permlane32_swap pair-pack (no LDS shuffle), exp2-folded gates
//     (scales baked into whh at preload and xw in k_prep), r->n->z dot order.
// (2) Megakernel: GRU block 0 + Q/K partial GEMMs (K=64..1023) + WO cvt run
//     concurrently; k_fix adds the rank-64 GRU term + residual afterwards.

namespace {

constexpr int B_ = 2, T_ = 2048, E_ = 1024, H_ = 16, HD_ = 64, G3_ = 192, M_ = B_ * T_;
constexpr float SRg = -1.4426950408889634f;  // -log2(e), r/z gates
constexpr float SNg = 2.8853900817779268f;   // 2*log2(e), n gate

typedef _Float16 f16;
typedef _Float16 f16x8 __attribute__((ext_vector_type(8)));
typedef _Float16 f16x4 __attribute__((ext_vector_type(4)));
typedef _Float16 f16x2 __attribute__((ext_vector_type(2)));
typedef float f32x4 __attribute__((ext_vector_type(4)));

__device__ __forceinline__ f32x4 mfma16(f16x8 a, f16x8 b, f32x4 c) {
  return __builtin_amdgcn_mfma_f32_16x16x32_f16(a, b, c, 0, 0, 0);
}

#if __has_builtin(__builtin_amdgcn_fdot2)
__device__ __forceinline__ float fdot2(f16x2 a, f16x2 b, float c) {
  return __builtin_amdgcn_fdot2(a, b, c, false);
}
#else
__device__ __forceinline__ float fdot2(f16x2 a, f16x2 b, float c) {
  return c + (float)a[0] * (float)b[0] + (float)a[1] * (float)b[1];
}
#endif

__device__ __forceinline__ float exp2_(float x) {
#if __has_builtin(__builtin_amdgcn_exp2f)
  return __builtin_amdgcn_exp2f(x);
#else
  return exp2f(x);
#endif
}
__device__ __forceinline__ float rcp_(float x) {
#if __has_builtin(__builtin_amdgcn_rcpf)
  return __builtin_amdgcn_rcpf(x);
#else
  return 1.f / x;
#endif
}

// ---------------- fp32 -> fp16 convert ----------------
__global__ __launch_bounds__(256) void k_cvt(const float* __restrict__ s,
                                             f16* __restrict__ d, int n) {
  int i = (blockIdx.x * 256 + threadIdx.x) * 4;
  if (i < n) {
    float4 v = *(const float4*)(s + i);
    f16x4 o = {(f16)v.x, (f16)v.y, (f16)v.z, (f16)v.w};
    *(f16x4*)(d + i) = o;
  }
}

// ---------------- prep: v = silu(x)*emb, x_proj pooling, xw = pool16(x)@wih^T
// xw written PRE-SCALED for exp2-based gates.
__global__ __launch_bounds__(256) void k_prep(
    const float* __restrict__ x, const int* __restrict__ tok,
    const f16* __restrict__ wihq, const f16* __restrict__ wihk,
    const float* __restrict__ v_emb,
    f16* __restrict__ vh, f16* __restrict__ aq, f16* __restrict__ ak,
    float* __restrict__ xwq, float* __restrict__ xwk) {
  __shared__ float xs[E_];
  __shared__ float xp[64];
  const int row = blockIdx.x;
  const int b = row >> 11, t = row & (T_ - 1);
  const int tid = threadIdx.x;
  const float* xrow = x + (size_t)row * E_;
  {
    const int tk = tok[row];
    float4 xv = ((const float4*)xrow)[tid];
    ((float4*)xs)[tid] = xv;
    float4 ev = ((const float4*)(v_emb + (size_t)tk * E_))[tid];
    f16x4 o;
    o[0] = (f16)(xv.x / (1.f + __expf(-xv.x)) * ev.x);
    o[1] = (f16)(xv.y / (1.f + __expf(-xv.y)) * ev.y);
    o[2] = (f16)(xv.z / (1.f + __expf(-xv.z)) * ev.z);
    o[3] = (f16)(xv.w / (1.f + __expf(-xv.w)) * ev.w);
    const int e0 = tid * 4;
    const size_t voff = ((size_t)(b * H_ + (e0 >> 6)) * T_ + t) * HD_ + (e0 & 63);
    *(f16x4*)(vh + voff) = o;
  }
  __syncthreads();
  if (tid < 64) {
    float s = 0.f;
#pragma unroll
    for (int j = 0; j < 16; ++j) s += xs[tid * 16 + j];
    xp[tid] = s * (1.f / 16.f);
  }
  for (int i = tid; i < 960; i += 256) {
    int s0 = (i * 1024) / 960;
    int e0 = ((i + 1) * 1024 + 959) / 960;
    float m = xs[s0];
    if (e0 - s0 == 2) m = (m + xs[s0 + 1]) * 0.5f;
    f16 hv = (f16)m;
    aq[(size_t)row * E_ + 64 + i] = hv;
    ak[(size_t)row * E_ + 64 + i] = hv;
  }
  __syncthreads();
  for (int o = tid; o < 2 * G3_; o += 256) {
    const int chain = o / G3_, g = o % G3_;
    const f16* wrow = (chain ? wihk : wihq) + g * 64;
    float acc = 0.f;
#pragma unroll
    for (int c = 0; c < 8; ++c) {
      f16x8 wv = *(const f16x8*)(wrow + c * 8);
#pragma unroll
      for (int u = 0; u < 8; ++u) acc += xp[c * 8 + u] * (float)wv[u];
    }
    const float sc = (g < 128) ? SRg : SNg;
    (chain ? xwk : xwq)[(size_t)row * G3_ + g] = acc * sc;
  }
}

// ---------------- GRU core: one wave, lane j owns h_j -----------------------
// pairs over K are (k, k+32); h-pair formed via v_permlane32_swap_b32 (VALU).
__device__ __forceinline__ void gru_core(const float* __restrict__ xw,
                                         const float* __restrict__ whh,
                                         f16* __restrict__ a, int lane) {
  f16x2 wr[32], wz[32], wn[32];
#pragma unroll
  for (int i = 0; i < 32; ++i) {
    wr[i] = {(f16)(whh[(size_t)lane * 64 + i] * SRg),
             (f16)(whh[(size_t)lane * 64 + i + 32] * SRg)};
    wz[i] = {(f16)(whh[(size_t)(64 + lane) * 64 + i] * SRg),
             (f16)(whh[(size_t)(64 + lane) * 64 + i + 32] * SRg)};
    wn[i] = {(f16)(whh[(size_t)(128 + lane) * 64 + i] * SNg),
             (f16)(whh[(size_t)(128 + lane) * 64 + i + 32] * SNg)};
  }
  float h = 0.f;
  float xr = xw[lane], xz = xw[64 + lane], xn = xw[128 + lane];
  for (int t = 0; t < T_; ++t) {
    // pack pair (h_l, h_{l+32}) into lanes l<32 via permlane32_swap
    const unsigned hu = (unsigned)__builtin_bit_cast(unsigned short, (f16)h);
    int va = (int)hu, vb = (int)hu;
    asm volatile("v_permlane32_swap_b32 %0, %1" : "+v"(va), "+v"(vb));
    const int pk = (int)(hu | ((unsigned)va << 16));
    int hp[32];
#pragma unroll
    for (int i = 0; i < 32; ++i) hp[i] = __builtin_amdgcn_readlane(pk, i);
    // prefetch next step's (pre-scaled) xw
    const int tn = (t + 1 < T_) ? t + 1 : t;
    const float* nx = xw + (size_t)tn * G3_;
    const float nxr = nx[lane], nxz = nx[64 + lane], nxn = nx[128 + lane];
    // r gate first (its exp hides under n dots)
    float ar = xr;
#pragma unroll
    for (int i = 0; i < 32; ++i)
      ar = fdot2(wr[i], __builtin_bit_cast(f16x2, hp[i]), ar);
    const float r = rcp_(1.f + exp2_(ar));
    float an = 0.f;
#pragma unroll
    for (int i = 0; i < 32; ++i)
      an = fdot2(wn[i], __builtin_bit_cast(f16x2, hp[i]), an);
    const float p2 = fmaf(r, an, xn);              // = 2*log2e*(xn + r*hwn)
    const float n = fmaf(-2.f, rcp_(1.f + exp2_(p2)), 1.f);  // tanh
    float az = xz;
#pragma unroll
    for (int i = 0; i < 32; ++i)
      az = fdot2(wz[i], __builtin_bit_cast(f16x2, hp[i]), az);
    const float z = rcp_(1.f + exp2_(az));
    h = fmaf(z, h - n, n);
    a[(size_t)t * E_ + lane] = (f16)h;
    xr = nxr; xz = nxz; xn = nxn;
  }
}

// ---------------- megakernel: GRU (block 0) + QK partial GEMMs + WO cvt -----
__global__ __launch_bounds__(256, 1) void k_mega(
    const float* __restrict__ xwq, const float* __restrict__ xwk,
    const float* __restrict__ whhq, const float* __restrict__ whhk,
    f16* __restrict__ aq, f16* __restrict__ ak,
    const f16* __restrict__ WQ, const f16* __restrict__ WK,
    float* __restrict__ QPRE, float* __restrict__ KPRE,
    const float* __restrict__ out_w, f16* __restrict__ WO) {
  __shared__ __align__(16) f16 As[128][72];
  __shared__ __align__(16) f16 Bs[128][72];
  const int bx = blockIdx.x;
  const int tid = threadIdx.x;
  if (bx == 0) {
    const int wid = tid >> 6, lane = tid & 63;
    const int qk = wid >> 1, b = wid & 1;
    const float* xw = (qk ? xwk : xwq) + (size_t)b * T_ * G3_;
    const float* whh = qk ? whhk : whhq;
    f16* a = (qk ? ak : aq) + (size_t)b * T_ * E_;
    gru_core(xw, whh, a, lane);
    return;
  }
  if (bx <= 512) {
    // partial GEMM: C = A[:,64:1024] @ W[:,64:1024]^T
    const int bid = bx - 1;
    const int chain = bid >> 8, tile = bid & 255;
    const int m0 = (tile >> 3) * 128, n0 = (tile & 7) * 128;
    const f16* A = chain ? ak : aq;
    const f16* W = chain ? WK : WQ;
    float* C = chain ? KPRE : QPRE;
    const int wid = tid >> 6, lane = tid & 63;
    const int wr = wid >> 1, wc = wid & 1;
    const int lg = lane >> 4, lc = lane & 15;
    f32x4 acc[4][4] = {};
    for (int kt = 64; kt < E_; kt += 64) {
#pragma unroll
      for (int it = 0; it < 4; ++it) {
        const int r = it * 32 + (tid >> 3);
        const int cs = (tid & 7) * 8;
        *(f16x8*)&As[r][cs] = *(const f16x8*)(A + (size_t)(m0 + r) * E_ + kt + cs);
        *(f16x8*)&Bs[r][cs] = *(const f16x8*)(W + (size_t)(n0 + r) * E_ + kt + cs);
      }
      __syncthreads();
      f16x8 af[4][2], bf[4][2];
#pragma unroll
      for (int mi = 0; mi < 4; ++mi)
#pragma unroll
        for (int ks = 0; ks < 2; ++ks) {
          af[mi][ks] = *(const f16x8*)&As[wr * 64 + mi * 16 + lc][ks * 32 + lg * 8];
          bf[mi][ks] = *(const f16x8*)&Bs[wc * 64 + mi * 16 + lc][ks * 32 + lg * 8];
        }
#pragma unroll
      for (int mi = 0; mi < 4; ++mi)
#pragma unroll
        for (int ni = 0; ni < 4; ++ni)
#pragma unroll
          for (int ks = 0; ks < 2; ++ks)
            acc[mi][ni] = mfma16(af[mi][ks], bf[ni][ks], acc[mi][ni]);
      __syncthreads();
    }
#pragma unroll
    for (int mi = 0; mi < 4; ++mi) {
      const int r0 = m0 + wr * 64 + mi * 16 + lg * 4;
#pragma unroll
      for (int ni = 0; ni < 4; ++ni) {
        const int col = n0 + wc * 64 + ni * 16 + lc;
#pragma unroll
        for (int q = 0; q < 4; ++q)
          C[(size_t)(r0 + q) * E_ + col] = acc[mi][ni][q];
      }
    }
    return;
  }
  // WO convert (8 blocks, grid-stride)
  {
    const int cb = bx - 513;
    for (int i = cb * 256 + tid; i < E_ * E_ / 4; i += 8 * 256) {
      float4 v = ((const float4*)out_w)[i];
      f16x4 o = {(f16)v.x, (f16)v.y, (f16)v.z, (f16)v.w};
      *(f16x4*)(WO + (size_t)i * 4) = o;
    }
  }
}

// ---------------- fix: C += A[:,0:64] @ W[:,0:64]^T + x (residual) ----------
__global__ __launch_bounds__(256) void k_fix(
    const f16* __restrict__ aq, const f16* __restrict__ ak,
    const f16* __restrict__ WQ, const f16* __restrict__ WK,
    const float* __restrict__ x, float* __restrict__ QPRE,
    float* __restrict__ KPRE) {
  __shared__ __align__(16) f16 As[128][72];
  __shared__ __align__(16) f16 Bs[128][72];
  const int chain = blockIdx.z;
  const f16* A = chain ? ak : aq;
  const f16* W = chain ? WK : WQ;
  float* C = chain ? KPRE : QPRE;
  const int m0 = blockIdx.x * 128, n0 = blockIdx.y * 128;
  const int tid = threadIdx.x;
  const int wid = tid >> 6, lane = tid & 63;
  const int wr = wid >> 1, wc = wid & 1;
  const int lg = lane >> 4, lc = lane & 15;
#pragma unroll
  for (int it = 0; it < 4; ++it) {
    const int r = it * 32 + (tid >> 3);
    const int cs = (tid & 7) * 8;
    *(f16x8*)&As[r][cs] = *(const f16x8*)(A + (size_t)(m0 + r) * E_ + cs);
    *(f16x8*)&Bs[r][cs] = *(const f16x8*)(W + (size_t)(n0 + r) * E_ + cs);
  }
  __syncthreads();
  f32x4 acc[4][4] = {};
  f16x8 af[4][2], bf[4][2];
#pragma unroll
  for (int mi = 0; mi < 4; ++mi)
#pragma unroll
    for (int ks = 0; ks < 2; ++ks) {
      af[mi][ks] = *(const f16x8*)&As[wr * 64 + mi * 16 + lc][ks * 32 + lg * 8];
      bf[mi][ks] = *(const f16x8*)&Bs[wc * 64 + mi * 16 + lc][ks * 32 + lg * 8];
    }
#pragma unroll
  for (int mi = 0; mi < 4; ++mi)
#pragma unroll
    for (int ni = 0; ni < 4; ++ni)
#pragma unroll
      for (int ks = 0; ks < 2; ++ks)
        acc[mi][ni] = mfma16(af[mi][ks], bf[ni][ks], acc[mi][ni]);
#pragma unroll
  for (int mi = 0; mi < 4; ++mi) {
    const int r0 = m0 + wr * 64 + mi * 16 + lg * 4;
#pragma unroll
    for (int ni = 0; ni < 4; ++ni) {
      const int col = n0 + wc * 64 + ni * 16 + lc;
#pragma unroll
      for (int q = 0; q < 4; ++q) {
        const size_t idx = (size_t)(r0 + q) * E_ + col;
        C[idx] += acc[mi][ni][q] + x[idx];
      }
    }
  }
}

// ---------------- LayerNorm (both chains), write f16 in [B,H,T,HD] ---------
__global__ __launch_bounds__(256) void k_ln(
    const float* __restrict__ qpre, const float* __restrict__ kpre,
    const float* __restrict__ qw, const float* __restrict__ qb,
    const float* __restrict__ kw, const float* __restrict__ kb,
    f16* __restrict__ qh, f16* __restrict__ kh) {
  const int chain = blockIdx.y;
  const float* pre = chain ? kpre : qpre;
  const float* gw = chain ? kw : qw;
  const float* gb = chain ? kb : qb;
  f16* outp = chain ? kh : qh;
  const int row = blockIdx.x;
  const int tid = threadIdx.x;
  const float4 v = ((const float4*)(pre + (size_t)row * E_))[tid];
  float s = v.x + v.y + v.z + v.w;
  float s2 = v.x * v.x + v.y * v.y + v.z * v.z + v.w * v.w;
#pragma unroll
  for (int off = 32; off; off >>= 1) {
    s += __shfl_xor(s, off);
    s2 += __shfl_xor(s2, off);
  }
  __shared__ float red[8];
  const int wid = tid >> 6, lane = tid & 63;
  if (!lane) { red[wid] = s; red[4 + wid] = s2; }
  __syncthreads();
  s = red[0] + red[1] + red[2] + red[3];
  s2 = red[4] + red[5] + red[6] + red[7];
  const float mu = s * (1.f / E_);
  const float inv = rsqrtf(s2 * (1.f / E_) - mu * mu + 1e-5f);
  const float4 w4 = ((const float4*)gw)[tid];
  const float4 b4 = ((const float4*)gb)[tid];
  const int e0 = tid * 4;
  f16x4 o;
  o[0] = (f16)((v.x - mu) * inv * w4.x + b4.x);
  o[1] = (f16)((v.y - mu) * inv * w4.y + b4.y);
  o[2] = (f16)((v.z - mu) * inv * w4.z + b4.z);
  o[3] = (f16)((v.w - mu) * inv * w4.w + b4.w);
  const int b = row >> 11, t = row & (T_ - 1);
  const size_t off2 = ((size_t)(b * H_ + (e0 >> 6)) * T_ + t) * HD_ + (e0 & 63);
  *(f16x4*)(outp + off2) = o;
}

// ---------------- flash attention: causal, scores*2/sqrt(64) = *0.25 -------
__global__ __launch_bounds__(256) void k_attn(const f16* __restrict__ Q,
                                              const f16* __restrict__ K,
                                              const f16* __restrict__ V,
                                              f16* __restrict__ AO) {
  __shared__ __align__(16) f16 Kt[64][72];
  __shared__ __align__(16) f16 Vt[64][72];
  __shared__ __align__(16) f16 Ps[4][16][72];
  const int qi = blockIdx.x, bh = blockIdx.y;
  const int b = bh >> 4, h = bh & 15;
  const int tid = threadIdx.x, wid = tid >> 6, lane = tid & 63;
  const int lg = lane >> 4, lc = lane & 15;
  const size_t hbase = (size_t)bh * T_ * HD_;
  const int qb = qi * 64;
  f16x8 qf[2];
  {
    const int qrow = qb + wid * 16 + lc;
#pragma unroll
    for (int ks = 0; ks < 2; ++ks)
      qf[ks] = *(const f16x8*)(Q + hbase + (size_t)qrow * HD_ + ks * 32 + lg * 8);
  }
  f32x4 o[4] = {};
  float m_run[4] = {-1e30f, -1e30f, -1e30f, -1e30f};
  float l_run[4] = {};
  const int qrow_d = qb + wid * 16 + lg * 4;
  for (int kt = 0; kt <= qi; ++kt) {
    {
      const int r = tid >> 2, cs = (tid & 3) * 16;
      const f16* ksrc = K + hbase + (size_t)(kt * 64 + r) * HD_ + cs;
      *(f16x8*)&Kt[r][cs] = *(const f16x8*)ksrc;
      *(f16x8*)&Kt[r][cs + 8] = *(const f16x8*)(ksrc + 8);
      const f16* vsrc = V + hbase + (size_t)(kt * 64 + lane) * HD_ + wid * 16;
      f16x8 va = *(const f16x8*)vsrc;
      f16x8 vb = *(const f16x8*)(vsrc + 8);
#pragma unroll
      for (int u = 0; u < 8; ++u) {
        Vt[wid * 16 + u][lane] = va[u];
        Vt[wid * 16 + 8 + u][lane] = vb[u];
      }
    }
    __syncthreads();
    f32x4 s[4] = {};
#pragma unroll
    for (int nt = 0; nt < 4; ++nt)
#pragma unroll
      for (int ks = 0; ks < 2; ++ks) {
        f16x8 kf = *(const f16x8*)&Kt[nt * 16 + lc][ks * 32 + lg * 8];
        s[nt] = mfma16(qf[ks], kf, s[nt]);
      }
    const bool diag = (kt == qi);
#pragma unroll
    for (int nt = 0; nt < 4; ++nt) {
      const int colg = kt * 64 + nt * 16 + lc;
#pragma unroll
      for (int r = 0; r < 4; ++r) {
        float v = s[nt][r] * 0.25f;
        if (diag && colg > qrow_d + r) v = -1e30f;
        s[nt][r] = v;
      }
    }
    float scalev[4];
#pragma unroll
    for (int r = 0; r < 4; ++r) {
      float m = fmaxf(fmaxf(s[0][r], s[1][r]), fmaxf(s[2][r], s[3][r]));
#pragma unroll
      for (int of = 1; of < 16; of <<= 1) m = fmaxf(m, __shfl_xor(m, of));
      const float mn = fmaxf(m_run[r], m);
      scalev[r] = __expf(m_run[r] - mn);
      m_run[r] = mn;
    }
    float ladd[4] = {};
#pragma unroll
    for (int nt = 0; nt < 4; ++nt)
#pragma unroll
      for (int r = 0; r < 4; ++r) {
        const float p = __expf(s[nt][r] - m_run[r]);
        s[nt][r] = p;
        ladd[r] += p;
      }
#pragma unroll
    for (int r = 0; r < 4; ++r) {
      float la = ladd[r];
#pragma unroll
      for (int of = 1; of < 16; of <<= 1) la += __shfl_xor(la, of);
      l_run[r] = l_run[r] * scalev[r] + la;
      o[0][r] *= scalev[r];
      o[1][r] *= scalev[r];
      o[2][r] *= scalev[r];
      o[3][r] *= scalev[r];
    }
#pragma unroll
    for (int nt = 0; nt < 4; ++nt)
#pragma unroll
      for (int r = 0; r < 4; ++r)
        Ps[wid][lg * 4 + r][nt * 16 + lc] = (f16)s[nt][r];
    f16x8 pf[2];
#pragma unroll
    for (int ks = 0; ks < 2; ++ks)
      pf[ks] = *(const f16x8*)&Ps[wid][lc][ks * 32 + lg * 8];
#pragma unroll
    for (int nt = 0; nt < 4; ++nt)
#pragma unroll
      for (int ks = 0; ks < 2; ++ks) {
        f16x8 vf = *(const f16x8*)&Vt[nt * 16 + lc][ks * 32 + lg * 8];
        o[nt] = mfma16(pf[ks], vf, o[nt]);
      }
    __syncthreads();
  }
#pragma unroll
  for (int nt = 0; nt < 4; ++nt)
#pragma unroll
    for (int r = 0; r < 4; ++r) {
      const float val = o[nt][r] / l_run[r];
      const int qrow = qrow_d + r;
      AO[((size_t)(b * T_ + qrow)) * E_ + h * HD_ + nt * 16 + lc] = (f16)val;
    }
}

// ---------------- out GEMM: C = A @ WO^T + bias -----------------------------
__global__ __launch_bounds__(256) void k_gemm_out(
    const f16* __restrict__ A, const f16* __restrict__ W,
    const float* __restrict__ bias, float* __restrict__ C) {
  __shared__ __align__(16) f16 As[128][72];
  __shared__ __align__(16) f16 Bs[128][72];
  const int m0 = blockIdx.x * 128, n0 = blockIdx.y * 128;
  const int tid = threadIdx.x;
  const int wid = tid >> 6, lane = tid & 63;
  const int wr = wid >> 1, wc = wid & 1;
  const int lg = lane >> 4, lc = lane & 15;
  f32x4 acc[4][4] = {};
  for (int kt = 0; kt < E_; kt += 64) {
#pragma unroll
    for (int it = 0; it < 4; ++it) {
      const int r = it * 32 + (tid >> 3);
      const int cs = (tid & 7) * 8;
      *(f16x8*)&As[r][cs] = *(const f16x8*)(A + (size_t)(m0 + r) * E_ + kt + cs);
      *(f16x8*)&Bs[r][cs] = *(const f16x8*)(W + (size_t)(n0 + r) * E_ + kt + cs);
    }
    __syncthreads();
    f16x8 af[4][2], bf[4][2];
#pragma unroll
    for (int mi = 0; mi < 4; ++mi)
#pragma unroll
      for (int ks = 0; ks < 2; ++ks) {
        af[mi][ks] = *(const f16x8*)&As[wr * 64 + mi * 16 + lc][ks * 32 + lg * 8];
        bf[mi][ks] = *(const f16x8*)&Bs[wc * 64 + mi * 16 + lc][ks * 32 + lg * 8];
      }
#pragma unroll
    for (int mi = 0; mi < 4; ++mi)
#pragma unroll
      for (int ni = 0; ni < 4; ++ni)
#pragma unroll
        for (int ks = 0; ks < 2; ++ks)
          acc[mi][ni] = mfma16(af[mi][ks], bf[ni][ks], acc[mi][ni]);
    __syncthreads();
  }
#pragma unroll
  for (int mi = 0; mi < 4; ++mi) {
    const int r0 = m0 + wr * 64 + mi * 16 + lg * 4;
#pragma unroll
    for (int ni = 0; ni < 4; ++ni) {
      const int col = n0 + wc * 64 + ni * 16 + lc;
      const float bv = bias[col];
#pragma unroll
      for (int q = 0; q < 4; ++q)
        C[(size_t)(r0 + q) * E_ + col] = acc[mi][ni][q] + bv;
    }
  }
}

}  // namespace

extern "C" void kernel_launch(void* const* d_in, const int* in_sizes, int n_in,
                              void* d_out, int out_size, void* d_ws, size_t ws_size,
                              hipStream_t stream) {
  (void)in_sizes; (void)n_in; (void)out_size; (void)ws_size;
  const float* x      = (const float*)d_in[0];
  const int*   tok    = (const int*)d_in[1];
  const float* q_wih  = (const float*)d_in[2];
  const float* q_whh  = (const float*)d_in[3];
  const float* q_lin  = (const float*)d_in[4];
  const float* k_wih  = (const float*)d_in[5];
  const float* k_whh  = (const float*)d_in[6];
  const float* k_lin  = (const float*)d_in[7];
  const float* v_emb  = (const float*)d_in[8];
  const float* q_ln_w = (const float*)d_in[9];
  const float* q_ln_b = (const float*)d_in[10];
  const float* k_ln_w = (const float*)d_in[11];
  const float* k_ln_b = (const float*)d_in[12];
  const float* out_w  = (const float*)d_in[13];
  const float* out_b  = (const float*)d_in[14];
  float* outp = (float*)d_out;

  char* ws = (char*)d_ws;
  size_t off = 0;
  auto take = [&](size_t bytes) -> void* {
    void* p = ws + off;
    off += (bytes + 255) & ~(size_t)255;
    return p;
  };
  f16* WQ   = (f16*)take((size_t)E_ * E_ * 2);
  f16* WK   = (f16*)take((size_t)E_ * E_ * 2);
  f16* WO   = (f16*)take((size_t)E_ * E_ * 2);
  f16* WIHQ = (f16*)take((size_t)G3_ * 64 * 2);
  f16* WIHK = (f16*)take((size_t)G3_ * 64 * 2);
  f16* AQ   = (f16*)take((size_t)M_ * E_ * 2);
  f16* AK   = (f16*)take((size_t)M_ * E_ * 2);
  f16* VH   = (f16*)take((size_t)M_ * E_ * 2);
  f16* QH   = (f16*)take((size_t)M_ * E_ * 2);
  f16* KH   = (f16*)take((size_t)M_ * E_ * 2);
  f16* AO   = (f16*)take((size_t)M_ * E_ * 2);
  float* XWQ  = (float*)take((size_t)M_ * G3_ * 4);
  float* XWK  = (float*)take((size_t)M_ * G3_ * 4);
  float* QPRE = (float*)take((size_t)M_ * E_ * 4);
  float* KPRE = (float*)take((size_t)M_ * E_ * 4);

  k_cvt<<<dim3((E_ * E_) / 1024), dim3(256), 0, stream>>>(q_lin, WQ, E_ * E_);
  k_cvt<<<dim3((E_ * E_) / 1024), dim3(256), 0, stream>>>(k_lin, WK, E_ * E_);
  k_cvt<<<dim3((G3_ * 64) / 1024), dim3(256), 0, stream>>>(q_wih, WIHQ, G3_ * 64);
  k_cvt<<<dim3((G3_ * 64) / 1024), dim3(256), 0, stream>>>(k_wih, WIHK, G3_ * 64);

  k_prep<<<dim3(M_), dim3(256), 0, stream>>>(x, tok, WIHQ, WIHK, v_emb, VH, AQ, AK, XWQ, XWK);

  k_mega<<<dim3(521), dim3(256), 0, stream>>>(XWQ, XWK, q_whh, k_whh, AQ, AK,
                                              WQ, WK, QPRE, KPRE, out_w, WO);

  k_fix<<<dim3(M_ / 128, E_ / 128, 2), dim3(256), 0, stream>>>(AQ, AK, WQ, WK, x, QPRE, KPRE);
  k_ln<<<dim3(M_, 2), dim3(256), 0, stream>>>(QPRE, KPRE, q_ln_w, q_ln_b, k_ln_w, k_ln_b, QH, KH);

  k_attn<<<dim3(T_ / 64, B_ * H_), dim3(256), 0, stream>>>(QH, KH, VH, AO);
  k_gemm_out<<<dim3(M_ / 128, E_ / 128), dim3(256), 0, stream>>>(AO, WO, out_b, outp);
}

// Round 7
// 879.939 us; speedup vs baseline: 1.7071x; 1.0033x over previous
//
#include <hip/hip_runtime.h>

// R7: GRU inner loop made issue-bound: readlane(i)+{r,n,z}-dot(i) interleaved
// (dep distance 3 instrs > fdot2 latency), s_setprio(3) on GRU waves.
// All f32->f16 weight cvts moved into the consuming kernels' staging paths
// (hidden under the GRU); x-residual folded into mega GEMM epilogue.

namespace {

constexpr int B_ = 2, T_ = 2048, E_ = 1024, H_ = 16, HD_ = 64, G3_ = 192, M_ = B_ * T_;
constexpr float SRg = -1.4426950408889634f;  // -log2(e), r/z gates
constexpr float SNg = 2.8853900817779268f;   // 2*log2(e), n gate

typedef _Float16 f16;
typedef _Float16 f16x8 __attribute__((ext_vector_type(8)));
typedef _Float16 f16x4 __attribute__((ext_vector_type(4)));
typedef _Float16 f16x2 __attribute__((ext_vector_type(2)));
typedef float f32x4 __attribute__((ext_vector_type(4)));

__device__ __forceinline__ f32x4 mfma16(f16x8 a, f16x8 b, f32x4 c) {
  return __builtin_amdgcn_mfma_f32_16x16x32_f16(a, b, c, 0, 0, 0);
}

#if __has_builtin(__builtin_amdgcn_fdot2)
__device__ __forceinline__ float fdot2(f16x2 a, f16x2 b, float c) {
  return __builtin_amdgcn_fdot2(a, b, c, false);
}
#else
__device__ __forceinline__ float fdot2(f16x2 a, f16x2 b, float c) {
  return c + (float)a[0] * (float)b[0] + (float)a[1] * (float)b[1];
}
#endif

__device__ __forceinline__ float exp2_(float x) {
#if __has_builtin(__builtin_amdgcn_exp2f)
  return __builtin_amdgcn_exp2f(x);
#else
  return exp2f(x);
#endif
}
__device__ __forceinline__ float rcp_(float x) {
#if __has_builtin(__builtin_amdgcn_rcpf)
  return __builtin_amdgcn_rcpf(x);
#else
  return 1.f / x;
#endif
}

// stage a 128x64 f32 tile -> f16 LDS [128][72]; same thread mapping as f16 path
__device__ __forceinline__ void stage_w_f32(const float* __restrict__ Wf,
                                            f16 (*Bs)[72], int n0, int kt,
                                            int tid) {
#pragma unroll
  for (int it = 0; it < 4; ++it) {
    const int r = it * 32 + (tid >> 3);
    const int cs = (tid & 7) * 8;
    const float* src = Wf + (size_t)(n0 + r) * E_ + kt + cs;
    float4 w0 = *(const float4*)src;
    float4 w1 = *(const float4*)(src + 4);
    f16x8 o = {(f16)w0.x, (f16)w0.y, (f16)w0.z, (f16)w0.w,
               (f16)w1.x, (f16)w1.y, (f16)w1.z, (f16)w1.w};
    *(f16x8*)&Bs[r][cs] = o;
  }
}

// ---------------- prep: v = silu(x)*emb, x_proj pooling, xw = pool16(x)@wih^T
// xw written PRE-SCALED for exp2-based gates. wih read as f32 (L2-resident).
__global__ __launch_bounds__(256) void k_prep(
    const float* __restrict__ x, const int* __restrict__ tok,
    const float* __restrict__ wihq, const float* __restrict__ wihk,
    const float* __restrict__ v_emb,
    f16* __restrict__ vh, f16* __restrict__ aq, f16* __restrict__ ak,
    float* __restrict__ xwq, float* __restrict__ xwk) {
  __shared__ float xs[E_];
  __shared__ float xp[64];
  const int row = blockIdx.x;
  const int b = row >> 11, t = row & (T_ - 1);
  const int tid = threadIdx.x;
  const float* xrow = x + (size_t)row * E_;
  {
    const int tk = tok[row];
    float4 xv = ((const float4*)xrow)[tid];
    ((float4*)xs)[tid] = xv;
    float4 ev = ((const float4*)(v_emb + (size_t)tk * E_))[tid];
    f16x4 o;
    o[0] = (f16)(xv.x / (1.f + __expf(-xv.x)) * ev.x);
    o[1] = (f16)(xv.y / (1.f + __expf(-xv.y)) * ev.y);
    o[2] = (f16)(xv.z / (1.f + __expf(-xv.z)) * ev.z);
    o[3] = (f16)(xv.w / (1.f + __expf(-xv.w)) * ev.w);
    const int e0 = tid * 4;
    const size_t voff = ((size_t)(b * H_ + (e0 >> 6)) * T_ + t) * HD_ + (e0 & 63);
    *(f16x4*)(vh + voff) = o;
  }
  __syncthreads();
  if (tid < 64) {
    float s = 0.f;
#pragma unroll
    for (int j = 0; j < 16; ++j) s += xs[tid * 16 + j];
    xp[tid] = s * (1.f / 16.f);
  }
  for (int i = tid; i < 960; i += 256) {
    int s0 = (i * 1024) / 960;
    int e0 = ((i + 1) * 1024 + 959) / 960;
    float m = xs[s0];
    if (e0 - s0 == 2) m = (m + xs[s0 + 1]) * 0.5f;
    f16 hv = (f16)m;
    aq[(size_t)row * E_ + 64 + i] = hv;
    ak[(size_t)row * E_ + 64 + i] = hv;
  }
  __syncthreads();
  for (int o = tid; o < 2 * G3_; o += 256) {
    const int chain = o / G3_, g = o % G3_;
    const float* wrow = (chain ? wihk : wihq) + (size_t)g * 64;
    float acc = 0.f;
#pragma unroll
    for (int c = 0; c < 16; ++c) {
      float4 wv = *(const float4*)(wrow + c * 4);
      acc += xp[c * 4] * wv.x + xp[c * 4 + 1] * wv.y +
             xp[c * 4 + 2] * wv.z + xp[c * 4 + 3] * wv.w;
    }
    const float sc = (g < 128) ? SRg : SNg;
    (chain ? xwk : xwq)[(size_t)row * G3_ + g] = acc * sc;
  }
}

// ---------------- GRU core: one wave, lane j owns h_j -----------------------
// pairs over K are (k, k+32); h-pair via v_permlane32_swap_b32; readlane and
// the 3 gate dots interleaved i-major so every chain is issue-bound.
__device__ __forceinline__ void gru_core(const float* __restrict__ xw,
                                         const float* __restrict__ whh,
                                         f16* __restrict__ a, int lane) {
  __builtin_amdgcn_s_setprio(3);  // protect serial chain from co-resident GEMM waves
  f16x2 wr[32], wz[32], wn[32];
#pragma unroll
  for (int i = 0; i < 32; ++i) {
    wr[i] = {(f16)(whh[(size_t)lane * 64 + i] * SRg),
             (f16)(whh[(size_t)lane * 64 + i + 32] * SRg)};
    wz[i] = {(f16)(whh[(size_t)(64 + lane) * 64 + i] * SRg),
             (f16)(whh[(size_t)(64 + lane) * 64 + i + 32] * SRg)};
    wn[i] = {(f16)(whh[(size_t)(128 + lane) * 64 + i] * SNg),
             (f16)(whh[(size_t)(128 + lane) * 64 + i + 32] * SNg)};
  }
  float h = 0.f;
  float xr = xw[lane], xz = xw[64 + lane], xn = xw[128 + lane];
  f16* ap = a + lane;
  for (int t = 0; t < T_; ++t) {
    // pack pair (h_l, h_{l+32}) into all lanes via permlane32_swap
    const unsigned hu = (unsigned)__builtin_bit_cast(unsigned short, (f16)h);
    int va = (int)hu, vb = (int)hu;
    asm volatile("v_permlane32_swap_b32 %0, %1" : "+v"(va), "+v"(vb));
    const int pk = (int)(hu | ((unsigned)va << 16));
    // prefetch next step's (pre-scaled) xw — consumed after the dots
    const int tn = (t + 1 < T_) ? t + 1 : t;
    const float* nx = xw + (size_t)tn * G3_;
    const float nxr = nx[lane], nxz = nx[64 + lane], nxn = nx[128 + lane];
    float ar = xr, az = xz, an = 0.f;
#pragma unroll
    for (int i = 0; i < 32; ++i) {
      const f16x2 hh = __builtin_bit_cast(f16x2, __builtin_amdgcn_readlane(pk, i));
      ar = fdot2(wr[i], hh, ar);
      an = fdot2(wn[i], hh, an);
      az = fdot2(wz[i], hh, az);
    }
    const float r = rcp_(1.f + exp2_(ar));
    const float p2 = fmaf(r, an, xn);               // 2*log2e*(xn + r*hwn)
    const float n = fmaf(-2.f, rcp_(1.f + exp2_(p2)), 1.f);  // tanh
    const float z = rcp_(1.f + exp2_(az));
    h = fmaf(z, h - n, n);
    ap[(size_t)t * E_] = (f16)h;
    xr = nxr; xz = nxz; xn = nxn;
  }
}

// ---------------- megakernel: GRU (block 0) + QK partial GEMMs (+x) + WO cvt
__global__ __launch_bounds__(256, 1) void k_mega(
    const float* __restrict__ xwq, const float* __restrict__ xwk,
    const float* __restrict__ whhq, const float* __restrict__ whhk,
    f16* __restrict__ aq, f16* __restrict__ ak,
    const float* __restrict__ WQf, const float* __restrict__ WKf,
    const float* __restrict__ x,
    float* __restrict__ QPRE, float* __restrict__ KPRE,
    const float* __restrict__ out_w, f16* __restrict__ WO) {
  __shared__ __align__(16) f16 As[128][72];
  __shared__ __align__(16) f16 Bs[128][72];
  const int bx = blockIdx.x;
  const int tid = threadIdx.x;
  if (bx == 0) {
    const int wid = tid >> 6, lane = tid & 63;
    const int qk = wid >> 1, b = wid & 1;
    const float* xw = (qk ? xwk : xwq) + (size_t)b * T_ * G3_;
    const float* whh = qk ? whhk : whhq;
    f16* a = (qk ? ak : aq) + (size_t)b * T_ * E_;
    gru_core(xw, whh, a, lane);
    return;
  }
  if (bx <= 512) {
    // partial GEMM: C = A[:,64:1024] @ W[:,64:1024]^T + x
    const int bid = bx - 1;
    const int chain = bid >> 8, tile = bid & 255;
    const int m0 = (tile >> 3) * 128, n0 = (tile & 7) * 128;
    const f16* A = chain ? ak : aq;
    const float* Wf = chain ? WKf : WQf;
    float* C = chain ? KPRE : QPRE;
    const int wid = tid >> 6, lane = tid & 63;
    const int wr = wid >> 1, wc = wid & 1;
    const int lg = lane >> 4, lc = lane & 15;
    f32x4 acc[4][4] = {};
    for (int kt = 64; kt < E_; kt += 64) {
#pragma unroll
      for (int it = 0; it < 4; ++it) {
        const int r = it * 32 + (tid >> 3);
        const int cs = (tid & 7) * 8;
        *(f16x8*)&As[r][cs] = *(const f16x8*)(A + (size_t)(m0 + r) * E_ + kt + cs);
      }
      stage_w_f32(Wf, Bs, n0, kt, tid);
      __syncthreads();
      f16x8 af[4][2], bf[4][2];
#pragma unroll
      for (int mi = 0; mi < 4; ++mi)
#pragma unroll
        for (int ks = 0; ks < 2; ++ks) {
          af[mi][ks] = *(const f16x8*)&As[wr * 64 + mi * 16 + lc][ks * 32 + lg * 8];
          bf[mi][ks] = *(const f16x8*)&Bs[wc * 64 + mi * 16 + lc][ks * 32 + lg * 8];
        }
#pragma unroll
      for (int mi = 0; mi < 4; ++mi)
#pragma unroll
        for (int ni = 0; ni < 4; ++ni)
#pragma unroll
          for (int ks = 0; ks < 2; ++ks)
            acc[mi][ni] = mfma16(af[mi][ks], bf[ni][ks], acc[mi][ni]);
      __syncthreads();
    }
#pragma unroll
    for (int mi = 0; mi < 4; ++mi) {
      const int r0 = m0 + wr * 64 + mi * 16 + lg * 4;
#pragma unroll
      for (int ni = 0; ni < 4; ++ni) {
        const int col = n0 + wc * 64 + ni * 16 + lc;
#pragma unroll
        for (int q = 0; q < 4; ++q) {
          const size_t idx = (size_t)(r0 + q) * E_ + col;
          C[idx] = acc[mi][ni][q] + x[idx];
        }
      }
    }
    return;
  }
  // WO convert (8 blocks, grid-stride) — hidden under GRU
  {
    const int cb = bx - 513;
    for (int i = cb * 256 + tid; i < E_ * E_ / 4; i += 8 * 256) {
      float4 v = ((const float4*)out_w)[i];
      f16x4 o = {(f16)v.x, (f16)v.y, (f16)v.z, (f16)v.w};
      *(f16x4*)(WO + (size_t)i * 4) = o;
    }
  }
}

// ---------------- fix: C += A[:,0:64] @ W[:,0:64]^T -------------------------
__global__ __launch_bounds__(256) void k_fix(
    const f16* __restrict__ aq, const f16* __restrict__ ak,
    const float* __restrict__ WQf, const float* __restrict__ WKf,
    float* __restrict__ QPRE, float* __restrict__ KPRE) {
  __shared__ __align__(16) f16 As[128][72];
  __shared__ __align__(16) f16 Bs[128][72];
  const int chain = blockIdx.z;
  const f16* A = chain ? ak : aq;
  const float* Wf = chain ? WKf : WQf;
  float* C = chain ? KPRE : QPRE;
  const int m0 = blockIdx.x * 128, n0 = blockIdx.y * 128;
  const int tid = threadIdx.x;
  const int wid = tid >> 6, lane = tid & 63;
  const int wr = wid >> 1, wc = wid & 1;
  const int lg = lane >> 4, lc = lane & 15;
#pragma unroll
  for (int it = 0; it < 4; ++it) {
    const int r = it * 32 + (tid >> 3);
    const int cs = (tid & 7) * 8;
    *(f16x8*)&As[r][cs] = *(const f16x8*)(A + (size_t)(m0 + r) * E_ + cs);
  }
  stage_w_f32(Wf, Bs, n0, 0, tid);
  __syncthreads();
  f32x4 acc[4][4] = {};
  f16x8 af[4][2], bf[4][2];
#pragma unroll
  for (int mi = 0; mi < 4; ++mi)
#pragma unroll
    for (int ks = 0; ks < 2; ++ks) {
      af[mi][ks] = *(const f16x8*)&As[wr * 64 + mi * 16 + lc][ks * 32 + lg * 8];
      bf[mi][ks] = *(const f16x8*)&Bs[wc * 64 + mi * 16 + lc][ks * 32 + lg * 8];
    }
#pragma unroll
  for (int mi = 0; mi < 4; ++mi)
#pragma unroll
    for (int ni = 0; ni < 4; ++ni)
#pragma unroll
      for (int ks = 0; ks < 2; ++ks)
        acc[mi][ni] = mfma16(af[mi][ks], bf[ni][ks], acc[mi][ni]);
#pragma unroll
  for (int mi = 0; mi < 4; ++mi) {
    const int r0 = m0 + wr * 64 + mi * 16 + lg * 4;
#pragma unroll
    for (int ni = 0; ni < 4; ++ni) {
      const int col = n0 + wc * 64 + ni * 16 + lc;
#pragma unroll
      for (int q = 0; q < 4; ++q) {
        const size_t idx = (size_t)(r0 + q) * E_ + col;
        C[idx] += acc[mi][ni][q];
      }
    }
  }
}

// ---------------- LayerNorm (both chains), write f16 in [B,H,T,HD] ---------
__global__ __launch_bounds__(256) void k_ln(
    const float* __restrict__ qpre, const float* __restrict__ kpre,
    const float* __restrict__ qw, const float* __restrict__ qb,
    const float* __restrict__ kw, const float* __restrict__ kb,
    f16* __restrict__ qh, f16* __restrict__ kh) {
  const int chain = blockIdx.y;
  const float* pre = chain ? kpre : qpre;
  const float* gw = chain ? kw : qw;
  const float* gb = chain ? kb : qb;
  f16* outp = chain ? kh : qh;
  const int row = blockIdx.x;
  const int tid = threadIdx.x;
  const float4 v = ((const float4*)(pre + (size_t)row * E_))[tid];
  float s = v.x + v.y + v.z + v.w;
  float s2 = v.x * v.x + v.y * v.y + v.z * v.z + v.w * v.w;
#pragma unroll
  for (int off = 32; off; off >>= 1) {
    s += __shfl_xor(s, off);
    s2 += __shfl_xor(s2, off);
  }
  __shared__ float red[8];
  const int wid = tid >> 6, lane = tid & 63;
  if (!lane) { red[wid] = s; red[4 + wid] = s2; }
  __syncthreads();
  s = red[0] + red[1] + red[2] + red[3];
  s2 = red[4] + red[5] + red[6] + red[7];
  const float mu = s * (1.f / E_);
  const float inv = rsqrtf(s2 * (1.f / E_) - mu * mu + 1e-5f);
  const float4 w4 = ((const float4*)gw)[tid];
  const float4 b4 = ((const float4*)gb)[tid];
  const int e0 = tid * 4;
  f16x4 o;
  o[0] = (f16)((v.x - mu) * inv * w4.x + b4.x);
  o[1] = (f16)((v.y - mu) * inv * w4.y + b4.y);
  o[2] = (f16)((v.z - mu) * inv * w4.z + b4.z);
  o[3] = (f16)((v.w - mu) * inv * w4.w + b4.w);
  const int b = row >> 11, t = row & (T_ - 1);
  const size_t off2 = ((size_t)(b * H_ + (e0 >> 6)) * T_ + t) * HD_ + (e0 & 63);
  *(f16x4*)(outp + off2) = o;
}

// ---------------- flash attention: causal, scores*2/sqrt(64) = *0.25 -------
__global__ __launch_bounds__(256) void k_attn(const f16* __restrict__ Q,
                                              const f16* __restrict__ K,
                                              const f16* __restrict__ V,
                                              f16* __restrict__ AO) {
  __shared__ __align__(16) f16 Kt[64][72];
  __shared__ __align__(16) f16 Vt[64][72];
  __shared__ __align__(16) f16 Ps[4][16][72];
  const int qi = blockIdx.x, bh = blockIdx.y;
  const int b = bh >> 4, h = bh & 15;
  const int tid = threadIdx.x, wid = tid >> 6, lane = tid & 63;
  const int lg = lane >> 4, lc = lane & 15;
  const size_t hbase = (size_t)bh * T_ * HD_;
  const int qb = qi * 64;
  f16x8 qf[2];
  {
    const int qrow = qb + wid * 16 + lc;
#pragma unroll
    for (int ks = 0; ks < 2; ++ks)
      qf[ks] = *(const f16x8*)(Q + hbase + (size_t)qrow * HD_ + ks * 32 + lg * 8);
  }
  f32x4 o[4] = {};
  float m_run[4] = {-1e30f, -1e30f, -1e30f, -1e30f};
  float l_run[4] = {};
  const int qrow_d = qb + wid * 16 + lg * 4;
  for (int kt = 0; kt <= qi; ++kt) {
    {
      const int r = tid >> 2, cs = (tid & 3) * 16;
      const f16* ksrc = K + hbase + (size_t)(kt * 64 + r) * HD_ + cs;
      *(f16x8*)&Kt[r][cs] = *(const f16x8*)ksrc;
      *(f16x8*)&Kt[r][cs + 8] = *(const f16x8*)(ksrc + 8);
      const f16* vsrc = V + hbase + (size_t)(kt * 64 + lane) * HD_ + wid * 16;
      f16x8 va = *(const f16x8*)vsrc;
      f16x8 vb = *(const f16x8*)(vsrc + 8);
#pragma unroll
      for (int u = 0; u < 8; ++u) {
        Vt[wid * 16 + u][lane] = va[u];
        Vt[wid * 16 + 8 + u][lane] = vb[u];
      }
    }
    __syncthreads();
    f32x4 s[4] = {};
#pragma unroll
    for (int nt = 0; nt < 4; ++nt)
#pragma unroll
      for (int ks = 0; ks < 2; ++ks) {
        f16x8 kf = *(const f16x8*)&Kt[nt * 16 + lc][ks * 32 + lg * 8];
        s[nt] = mfma16(qf[ks], kf, s[nt]);
      }
    const bool diag = (kt == qi);
#pragma unroll
    for (int nt = 0; nt < 4; ++nt) {
      const int colg = kt * 64 + nt * 16 + lc;
#pragma unroll
      for (int r = 0; r < 4; ++r) {
        float v = s[nt][r] * 0.25f;
        if (diag && colg > qrow_d + r) v = -1e30f;
        s[nt][r] = v;
      }
    }
    float scalev[4];
#pragma unroll
    for (int r = 0; r < 4; ++r) {
      float m = fmaxf(fmaxf(s[0][r], s[1][r]), fmaxf(s[2][r], s[3][r]));
#pragma unroll
      for (int of = 1; of < 16; of <<= 1) m = fmaxf(m, __shfl_xor(m, of));
      const float mn = fmaxf(m_run[r], m);
      scalev[r] = __expf(m_run[r] - mn);
      m_run[r] = mn;
    }
    float ladd[4] = {};
#pragma unroll
    for (int nt = 0; nt < 4; ++nt)
#pragma unroll
      for (int r = 0; r < 4; ++r) {
        const float p = __expf(s[nt][r] - m_run[r]);
        s[nt][r] = p;
        ladd[r] += p;
      }
#pragma unroll
    for (int r = 0; r < 4; ++r) {
      float la = ladd[r];
#pragma unroll
      for (int of = 1; of < 16; of <<= 1) la += __shfl_xor(la, of);
      l_run[r] = l_run[r] * scalev[r] + la;
      o[0][r] *= scalev[r];
      o[1][r] *= scalev[r];
      o[2][r] *= scalev[r];
      o[3][r] *= scalev[r];
    }
#pragma unroll
    for (int nt = 0; nt < 4; ++nt)
#pragma unroll
      for (int r = 0; r < 4; ++r)
        Ps[wid][lg * 4 + r][nt * 16 + lc] = (f16)s[nt][r];
    f16x8 pf[2];
#pragma unroll
    for (int ks = 0; ks < 2; ++ks)
      pf[ks] = *(const f16x8*)&Ps[wid][lc][ks * 32 + lg * 8];
#pragma unroll
    for (int nt = 0; nt < 4; ++nt)
#pragma unroll
      for (int ks = 0; ks < 2; ++ks) {
        f16x8 vf = *(const f16x8*)&Vt[nt * 16 + lc][ks * 32 + lg * 8];
        o[nt] = mfma16(pf[ks], vf, o[nt]);
      }
    __syncthreads();
  }
#pragma unroll
  for (int nt = 0; nt < 4; ++nt)
#pragma unroll
    for (int r = 0; r < 4; ++r) {
      const float val = o[nt][r] / l_run[r];
      const int qrow = qrow_d + r;
      AO[((size_t)(b * T_ + qrow)) * E_ + h * HD_ + nt * 16 + lc] = (f16)val;
    }
}

// ---------------- out GEMM: C = A @ WO^T + bias -----------------------------
__global__ __launch_bounds__(256) void k_gemm_out(
    const f16* __restrict__ A, const f16* __restrict__ W,
    const float* __restrict__ bias, float* __restrict__ C) {
  __shared__ __align__(16) f16 As[128][72];
  __shared__ __align__(16) f16 Bs[128][72];
  const int m0 = blockIdx.x * 128, n0 = blockIdx.y * 128;
  const int tid = threadIdx.x;
  const int wid = tid >> 6, lane = tid & 63;
  const int wr = wid >> 1, wc = wid & 1;
  const int lg = lane >> 4, lc = lane & 15;
  f32x4 acc[4][4] = {};
  for (int kt = 0; kt < E_; kt += 64) {
#pragma unroll
    for (int it = 0; it < 4; ++it) {
      const int r = it * 32 + (tid >> 3);
      const int cs = (tid & 7) * 8;
      *(f16x8*)&As[r][cs] = *(const f16x8*)(A + (size_t)(m0 + r) * E_ + kt + cs);
      *(f16x8*)&Bs[r][cs] = *(const f16x8*)(W + (size_t)(n0 + r) * E_ + kt + cs);
    }
    __syncthreads();
    f16x8 af[4][2], bf[4][2];
#pragma unroll
    for (int mi = 0; mi < 4; ++mi)
#pragma unroll
      for (int ks = 0; ks < 2; ++ks) {
        af[mi][ks] = *(const f16x8*)&As[wr * 64 + mi * 16 + lc][ks * 32 + lg * 8];
        bf[mi][ks] = *(const f16x8*)&Bs[wc * 64 + mi * 16 + lc][ks * 32 + lg * 8];
      }
#pragma unroll
    for (int mi = 0; mi < 4; ++mi)
#pragma unroll
      for (int ni = 0; ni < 4; ++ni)
#pragma unroll
        for (int ks = 0; ks < 2; ++ks)
          acc[mi][ni] = mfma16(af[mi][ks], bf[ni][ks], acc[mi][ni]);
    __syncthreads();
  }
#pragma unroll
  for (int mi = 0; mi < 4; ++mi) {
    const int r0 = m0 + wr * 64 + mi * 16 + lg * 4;
#pragma unroll
    for (int ni = 0; ni < 4; ++ni) {
      const int col = n0 + wc * 64 + ni * 16 + lc;
      const float bv = bias[col];
#pragma unroll
      for (int q = 0; q < 4; ++q)
        C[(size_t)(r0 + q) * E_ + col] = acc[mi][ni][q] + bv;
    }
  }
}

}  // namespace

extern "C" void kernel_launch(void* const* d_in, const int* in_sizes, int n_in,
                              void* d_out, int out_size, void* d_ws, size_t ws_size,
                              hipStream_t stream) {
  (void)in_sizes; (void)n_in; (void)out_size; (void)ws_size;
  const float* x      = (const float*)d_in[0];
  const int*   tok    = (const int*)d_in[1];
  const float* q_wih  = (const float*)d_in[2];
  const float* q_whh  = (const float*)d_in[3];
  const float* q_lin  = (const float*)d_in[4];
  const float* k_wih  = (const float*)d_in[5];
  const float* k_whh  = (const float*)d_in[6];
  const float* k_lin  = (const float*)d_in[7];
  const float* v_emb  = (const float*)d_in[8];
  const float* q_ln_w = (const float*)d_in[9];
  const float* q_ln_b = (const float*)d_in[10];
  const float* k_ln_w = (const float*)d_in[11];
  const float* k_ln_b = (const float*)d_in[12];
  const float* out_w  = (const float*)d_in[13];
  const float* out_b  = (const float*)d_in[14];
  float* outp = (float*)d_out;

  char* ws = (char*)d_ws;
  size_t off = 0;
  auto take = [&](size_t bytes) -> void* {
    void* p = ws + off;
    off += (bytes + 255) & ~(size_t)255;
    return p;
  };
  f16* WO   = (f16*)take((size_t)E_ * E_ * 2);
  f16* AQ   = (f16*)take((size_t)M_ * E_ * 2);
  f16* AK   = (f16*)take((size_t)M_ * E_ * 2);
  f16* VH   = (f16*)take((size_t)M_ * E_ * 2);
  f16* QH   = (f16*)take((size_t)M_ * E_ * 2);
  f16* KH   = (f16*)take((size_t)M_ * E_ * 2);
  f16* AO   = (f16*)take((size_t)M_ * E_ * 2);
  float* XWQ  = (float*)take((size_t)M_ * G3_ * 4);
  float* XWK  = (float*)take((size_t)M_ * G3_ * 4);
  float* QPRE = (float*)take((size_t)M_ * E_ * 4);
  float* KPRE = (float*)take((size_t)M_ * E_ * 4);

  k_prep<<<dim3(M_), dim3(256), 0, stream>>>(x, tok, q_wih, k_wih, v_emb, VH, AQ, AK, XWQ, XWK);

  k_mega<<<dim3(521), dim3(256), 0, stream>>>(XWQ, XWK, q_whh, k_whh, AQ, AK,
                                              q_lin, k_lin, x, QPRE, KPRE, out_w, WO);

  k_fix<<<dim3(M_ / 128, E_ / 128, 2), dim3(256), 0, stream>>>(AQ, AK, q_lin, k_lin, QPRE, KPRE);
  k_ln<<<dim3(M_, 2), dim3(256), 0, stream>>>(QPRE, KPRE, q_ln_w, q_ln_b, k_ln_w, k_ln_b, QH, KH);

  k_attn<<<dim3(T_ / 64, B_ * H_), dim3(256), 0, stream>>>(QH, KH, VH, AO);
  k_gemm_out<<<dim3(M_ / 128, E_ / 128), dim3(256), 0, stream>>>(AO, WO, out_b, outp);
}